// Round 6
// baseline (2113.457 us; speedup 1.0000x reference)
//
#include <hip/hip_runtime.h>
#include <math.h>

#define N_TOK   65536
#define HID     1024
#define NEXP    64
#define EPSF    1e-12f

// ---------------- prep: ws[0..63] = 1/||sim col||, ws[64..127] = sigmoid(gates)
__global__ __launch_bounds__(256) void prep_kernel(const float* __restrict__ sim,
                                                   const float* __restrict__ gates,
                                                   float* __restrict__ ws) {
    __shared__ float partial[4][64];
    int e = threadIdx.x & 63;
    int q = threadIdx.x >> 6;   // 0..3
    float s = 0.f;
    for (int h = q * 256; h < q * 256 + 256; ++h) {
        float v = sim[h * NEXP + e];
        s += v * v;
    }
    partial[q][e] = s;
    __syncthreads();
    if (threadIdx.x < 64) {
        float ss = partial[0][e] + partial[1][e] + partial[2][e] + partial[3][e];
        ws[e] = 1.0f / fmaxf(sqrtf(ss), EPSF);
        ws[64 + e] = 1.0f / (1.0f + expf(-gates[e]));
    }
}

// ---------------- prep2: natural-layout normalized W: wn[k*64+e] = sim[k*64+e]*invcol[e]
// (single f32 mul, identical rounding to all passing rounds)
__global__ __launch_bounds__(256) void prep2n_kernel(const float* __restrict__ sim,
                                                     const float* __restrict__ ws_ro,
                                                     float* __restrict__ wn) {
    int idx = blockIdx.x * 256 + threadIdx.x;   // 0..65535
    wn[idx] = sim[idx] * ws_ro[idx & 63];
}

// ---------------- main kernel v6: 256 threads = 4 independent waves, no barriers.
// Wave handles 16 tokens; thread tile 2 tok x 8 exp (16 acc VGPRs).
// x: transposed per-wave LDS tile [2][32 k][16 tok + pad2], ds_read_b64.
// W: VMEM float4 stream (L2-resident normalized copy), depth-2 k prefetch.
__global__ __launch_bounds__(256, 4) void gate_v6_kernel(const float* __restrict__ x,
                                                         const float* __restrict__ wn,
                                                         const float* __restrict__ prep,
                                                         float* __restrict__ out) {
    __shared__ __align__(16) float xs[4][2][32][18];

    const int tid  = threadIdx.x;
    const int lane = tid & 63;
    const int wv   = tid >> 6;               // wave 0..3 (block-uniform per wave)
    const int tg   = lane >> 3;              // token group 0..7 -> tokens 2tg,2tg+1
    const int eg   = lane & 7;               // expert group -> experts eg*8..+7
    const int e0   = eg * 8;
    const int tw   = blockIdx.x * 64 + wv * 16;   // wave's 16-token base
    const int rA   = 2 * tg, rB = rA + 1;         // local token rows

    // staging: lane loads k-quad eg*4..eg*4+3 of rows rA and rB each chunk
    const float* gA = x + (size_t)(tw + rA) * HID + eg * 4;
    const float* gB = x + (size_t)(tw + rB) * HID + eg * 4;

    float acc[2][8];
#pragma unroll
    for (int j = 0; j < 2; ++j)
#pragma unroll
        for (int i = 0; i < 8; ++i) acc[j][i] = 0.f;
    float ssA = 0.f, ssB = 0.f;

    // ---- prologue: stage chunk 0, fuse ss (k-ascending per-lane subsequence)
    {
        float4 fA = *(const float4*)gA;
        float4 fB = *(const float4*)gB;
        const float a[4] = { fA.x, fA.y, fA.z, fA.w };
        const float b[4] = { fB.x, fB.y, fB.z, fB.w };
#pragma unroll
        for (int i = 0; i < 4; ++i) {
            ssA = fmaf(a[i], a[i], ssA);
            ssB = fmaf(b[i], b[i], ssB);
            xs[wv][0][eg * 4 + i][rA] = a[i];
            xs[wv][0][eg * 4 + i][rB] = b[i];
        }
    }

#pragma unroll 1
    for (int c = 0; c < 32; ++c) {
        // issue next chunk's x loads early (consumed after compute)
        float4 nA, nB;
        if (c < 31) {
            nA = *(const float4*)(gA + (c + 1) * 32);
            nB = *(const float4*)(gB + (c + 1) * 32);
        }

        const float (*xb)[18] = xs[wv][c & 1];
        const float* wbase = wn + (size_t)c * 32 * NEXP + e0;

        // W prefetch pipeline, depth 2 k-steps
        float4 a0 = *(const float4*)(wbase);
        float4 b0 = *(const float4*)(wbase + 4);
        float4 a1 = *(const float4*)(wbase + 64);
        float4 b1 = *(const float4*)(wbase + 68);

#pragma unroll 8
        for (int k = 0; k < 32; k += 2) {
            float4 na0, nb0, na1, nb1;
            if (k + 2 < 32) {
                na0 = *(const float4*)(wbase + (k + 2) * 64);
                nb0 = *(const float4*)(wbase + (k + 2) * 64 + 4);
                na1 = *(const float4*)(wbase + (k + 3) * 64);
                nb1 = *(const float4*)(wbase + (k + 3) * 64 + 4);
            }
            const float2 x0 = *(const float2*)&xb[k][rA];
            const float2 x1 = *(const float2*)&xb[k + 1][rA];
            {
                const float w0[8] = { a0.x, a0.y, a0.z, a0.w, b0.x, b0.y, b0.z, b0.w };
#pragma unroll
                for (int i = 0; i < 8; ++i) {
                    acc[0][i] = fmaf(x0.x, w0[i], acc[0][i]);
                    acc[1][i] = fmaf(x0.y, w0[i], acc[1][i]);
                }
            }
            {
                const float w1[8] = { a1.x, a1.y, a1.z, a1.w, b1.x, b1.y, b1.z, b1.w };
#pragma unroll
                for (int i = 0; i < 8; ++i) {
                    acc[0][i] = fmaf(x1.x, w1[i], acc[0][i]);
                    acc[1][i] = fmaf(x1.y, w1[i], acc[1][i]);
                }
            }
            a0 = na0; b0 = nb0; a1 = na1; b1 = nb1;
        }

        // stage chunk c+1 into the other buffer, fuse ss (DS in-order per wave)
        if (c < 31) {
            const int nb_ = (c + 1) & 1;
            const float a[4] = { nA.x, nA.y, nA.z, nA.w };
            const float b[4] = { nB.x, nB.y, nB.z, nB.w };
#pragma unroll
            for (int i = 0; i < 4; ++i) {
                ssA = fmaf(a[i], a[i], ssA);
                ssB = fmaf(b[i], b[i], ssB);
                xs[wv][nb_][eg * 4 + i][rA] = a[i];
                xs[wv][nb_][eg * 4 + i][rB] = b[i];
            }
        }
    }

    // ---- row-norm reduce across the 8 eg lanes of this token group ----
    ssA += __shfl_xor(ssA, 1, 8);
    ssA += __shfl_xor(ssA, 2, 8);
    ssA += __shfl_xor(ssA, 4, 8);
    ssB += __shfl_xor(ssB, 1, 8);
    ssB += __shfl_xor(ssB, 2, 8);
    ssB += __shfl_xor(ssB, 4, 8);
    const float invA = 1.0f / fmaxf(sqrtf(ssA), EPSF);
    const float invB = 1.0f / fmaxf(sqrtf(ssB), EPSF);

    float thr[8];
#pragma unroll
    for (int i = 0; i < 8; ++i) thr[i] = prep[64 + e0 + i];

    const size_t out_pre  = (size_t)N_TOK * NEXP;
    const size_t out_mask = 2 * (size_t)N_TOK * NEXP;

    // ---- epilogue: round-1-proven 8-lane/token path, j over 2 tokens ----
#pragma unroll
    for (int j = 0; j < 2; ++j) {
        const float inv = j ? invB : invA;
        const int t = tw + rA + j;
        float logit[8], pre[8], gated[8];
        int active[8];
        int myact = 0;
#pragma unroll
        for (int i = 0; i < 8; ++i) {
            logit[i] = acc[j][i] * inv;
            pre[i]   = logit[i] - thr[i];
            gated[i] = fmaxf(pre[i], 0.f);
            active[i] = pre[i] > 0.f;
            myact += active[i];
        }
        int rowact = myact;
        rowact += __shfl_xor(rowact, 1, 8);
        rowact += __shfl_xor(rowact, 2, 8);
        rowact += __shfl_xor(rowact, 4, 8);

        float probs[8], mask[8];
        if (rowact > 0) {
            float m = -INFINITY;
#pragma unroll
            for (int i = 0; i < 8; ++i) m = fmaxf(m, active[i] ? gated[i] : -INFINITY);
            m = fmaxf(m, __shfl_xor(m, 1, 8));
            m = fmaxf(m, __shfl_xor(m, 2, 8));
            m = fmaxf(m, __shfl_xor(m, 4, 8));
            float s = 0.f;
#pragma unroll
            for (int i = 0; i < 8; ++i) {
                float ev = active[i] ? expf(gated[i] - m) : 0.f;
                probs[i] = ev; s += ev;
            }
            s += __shfl_xor(s, 1, 8);
            s += __shfl_xor(s, 2, 8);
            s += __shfl_xor(s, 4, 8);
            float rs = 1.0f / s;
#pragma unroll
            for (int i = 0; i < 8; ++i) {
                probs[i] *= rs;
                mask[i] = active[i] ? 1.f : 0.f;
            }
        } else {
            // top-32 fallback: exact 32nd-largest via radix descent on order keys
            unsigned key[8];
#pragma unroll
            for (int i = 0; i < 8; ++i) {
                unsigned u = __float_as_uint(logit[i]);
                key[i] = (u & 0x80000000u) ? ~u : (u | 0x80000000u);
            }
            unsigned cand = 0u;
            for (int bit = 31; bit >= 0; --bit) {
                unsigned test = cand | (1u << bit);
                int c = 0;
#pragma unroll
                for (int i = 0; i < 8; ++i) c += (key[i] >= test);
                c += __shfl_xor(c, 1, 8);
                c += __shfl_xor(c, 2, 8);
                c += __shfl_xor(c, 4, 8);
                if (c >= 32) cand = test;
            }
            int cgt = 0;
#pragma unroll
            for (int i = 0; i < 8; ++i) cgt += (key[i] > cand);
            cgt += __shfl_xor(cgt, 1, 8);
            cgt += __shfl_xor(cgt, 2, 8);
            cgt += __shfl_xor(cgt, 4, 8);
            int need_eq = 32 - cgt;

            int eqc = 0;
#pragma unroll
            for (int i = 0; i < 8; ++i) eqc += (key[i] == cand);
            int scan = eqc, tmp;
            tmp = __shfl_up(scan, 1, 8); if (eg >= 1) scan += tmp;
            tmp = __shfl_up(scan, 2, 8); if (eg >= 2) scan += tmp;
            tmp = __shfl_up(scan, 4, 8); if (eg >= 4) scan += tmp;
            int run = scan - eqc;   // ties with smaller global index
#pragma unroll
            for (int i = 0; i < 8; ++i) {
                int sel = (key[i] > cand) || ((key[i] == cand) && (run < need_eq));
                run += (key[i] == cand);
                mask[i]  = sel ? 1.f : 0.f;
                probs[i] = sel ? 0.03125f : 0.f;   // gated==0 on fallback rows
            }
        }

        const size_t row = (size_t)t * NEXP + e0;
        *(float4*)&out[row]                = make_float4(probs[0], probs[1], probs[2], probs[3]);
        *(float4*)&out[row + 4]            = make_float4(probs[4], probs[5], probs[6], probs[7]);
        *(float4*)&out[out_pre + row]      = make_float4(pre[0], pre[1], pre[2], pre[3]);
        *(float4*)&out[out_pre + row + 4]  = make_float4(pre[4], pre[5], pre[6], pre[7]);
        *(float4*)&out[out_mask + row]     = make_float4(mask[0], mask[1], mask[2], mask[3]);
        *(float4*)&out[out_mask + row + 4] = make_float4(mask[4], mask[5], mask[6], mask[7]);
    }
}

// ---------------- fallback (verbatim round-1 kernel, used only if ws too small)
#define TOKB    128
#define KC      64
#define XPAD    65

__global__ __launch_bounds__(256) void gate_kernel_fb(const float* __restrict__ x,
                                                      const float* __restrict__ sim,
                                                      const float* __restrict__ prep,
                                                      float* __restrict__ out) {
    __shared__ float x_lds[TOKB][XPAD];
    __shared__ float w_lds[KC][NEXP];
    __shared__ float ss_lds[TOKB];
    __shared__ float invcol[NEXP];
    __shared__ float thr_s[NEXP];

    const int tid = threadIdx.x;
    const int base_t = blockIdx.x * TOKB;

    if (tid < NEXP) { invcol[tid] = prep[tid]; thr_s[tid] = prep[64 + tid]; }
    if (tid < TOKB) ss_lds[tid] = 0.f;

    const int g_e = tid & 7;
    const int g_t = tid >> 3;
    const int e0 = g_e * 8;
    const int t0 = g_t * 4;

    const int lt = tid >> 4;
    const int lk = (tid & 15) * 4;

    float acc[4][8];
#pragma unroll
    for (int j = 0; j < 4; ++j)
#pragma unroll
        for (int i = 0; i < 8; ++i) acc[j][i] = 0.f;

    for (int kc = 0; kc < HID; kc += KC) {
        __syncthreads();
#pragma unroll
        for (int it = 0; it < 4; ++it) {
            int flat4 = it * 256 + tid;
            int k = flat4 >> 4;
            int e = (flat4 & 15) * 4;
            float4 v = *(const float4*)&sim[(size_t)(kc + k) * NEXP + e];
            v.x *= invcol[e]; v.y *= invcol[e + 1]; v.z *= invcol[e + 2]; v.w *= invcol[e + 3];
            *(float4*)&w_lds[k][e] = v;
        }
#pragma unroll
        for (int it = 0; it < 8; ++it) {
            int t = it * 16 + lt;
            float4 v = *(const float4*)&x[(size_t)(base_t + t) * HID + kc + lk];
            x_lds[t][lk + 0] = v.x; x_lds[t][lk + 1] = v.y;
            x_lds[t][lk + 2] = v.z; x_lds[t][lk + 3] = v.w;
            float s4 = v.x * v.x + v.y * v.y + v.z * v.z + v.w * v.w;
            s4 += __shfl_xor(s4, 1, 16);
            s4 += __shfl_xor(s4, 2, 16);
            s4 += __shfl_xor(s4, 4, 16);
            s4 += __shfl_xor(s4, 8, 16);
            if ((tid & 15) == 0) ss_lds[t] += s4;
        }
        __syncthreads();
#pragma unroll 8
        for (int k = 0; k < KC; ++k) {
            float x0 = x_lds[t0 + 0][k];
            float x1 = x_lds[t0 + 1][k];
            float x2 = x_lds[t0 + 2][k];
            float x3 = x_lds[t0 + 3][k];
            float4 w0 = *(const float4*)&w_lds[k][e0];
            float4 w1 = *(const float4*)&w_lds[k][e0 + 4];
            float wv[8] = { w0.x, w0.y, w0.z, w0.w, w1.x, w1.y, w1.z, w1.w };
#pragma unroll
            for (int i = 0; i < 8; ++i) {
                acc[0][i] += x0 * wv[i];
                acc[1][i] += x1 * wv[i];
                acc[2][i] += x2 * wv[i];
                acc[3][i] += x3 * wv[i];
            }
        }
    }

    const size_t out_pre  = (size_t)N_TOK * NEXP;
    const size_t out_mask = 2 * (size_t)N_TOK * NEXP;

#pragma unroll
    for (int j = 0; j < 4; ++j) {
        int t = t0 + j;
        float inv = 1.0f / fmaxf(sqrtf(ss_lds[t]), EPSF);
        float logit[8], pre[8], gated[8];
        int active[8];
        int myact = 0;
#pragma unroll
        for (int i = 0; i < 8; ++i) {
            logit[i] = acc[j][i] * inv;
            pre[i]   = logit[i] - thr_s[e0 + i];
            gated[i] = fmaxf(pre[i], 0.f);
            active[i] = pre[i] > 0.f;
            myact += active[i];
        }
        int rowact = myact;
        rowact += __shfl_xor(rowact, 1, 8);
        rowact += __shfl_xor(rowact, 2, 8);
        rowact += __shfl_xor(rowact, 4, 8);

        float probs[8], mask[8];
        if (rowact > 0) {
            float m = -INFINITY;
#pragma unroll
            for (int i = 0; i < 8; ++i) m = fmaxf(m, active[i] ? gated[i] : -INFINITY);
            m = fmaxf(m, __shfl_xor(m, 1, 8));
            m = fmaxf(m, __shfl_xor(m, 2, 8));
            m = fmaxf(m, __shfl_xor(m, 4, 8));
            float s = 0.f;
#pragma unroll
            for (int i = 0; i < 8; ++i) {
                float ev = active[i] ? expf(gated[i] - m) : 0.f;
                probs[i] = ev; s += ev;
            }
            s += __shfl_xor(s, 1, 8);
            s += __shfl_xor(s, 2, 8);
            s += __shfl_xor(s, 4, 8);
            float rs = 1.0f / s;
#pragma unroll
            for (int i = 0; i < 8; ++i) {
                probs[i] *= rs;
                mask[i] = active[i] ? 1.f : 0.f;
            }
        } else {
            unsigned key[8];
#pragma unroll
            for (int i = 0; i < 8; ++i) {
                unsigned u = __float_as_uint(logit[i]);
                key[i] = (u & 0x80000000u) ? ~u : (u | 0x80000000u);
            }
            unsigned cand = 0u;
            for (int bit = 31; bit >= 0; --bit) {
                unsigned test = cand | (1u << bit);
                int c = 0;
#pragma unroll
                for (int i = 0; i < 8; ++i) c += (key[i] >= test);
                c += __shfl_xor(c, 1, 8);
                c += __shfl_xor(c, 2, 8);
                c += __shfl_xor(c, 4, 8);
                if (c >= 32) cand = test;
            }
            int cgt = 0;
#pragma unroll
            for (int i = 0; i < 8; ++i) cgt += (key[i] > cand);
            cgt += __shfl_xor(cgt, 1, 8);
            cgt += __shfl_xor(cgt, 2, 8);
            cgt += __shfl_xor(cgt, 4, 8);
            int need_eq = 32 - cgt;

            int eqc = 0;
#pragma unroll
            for (int i = 0; i < 8; ++i) eqc += (key[i] == cand);
            int scan = eqc, tmp;
            tmp = __shfl_up(scan, 1, 8); if (g_e >= 1) scan += tmp;
            tmp = __shfl_up(scan, 2, 8); if (g_e >= 2) scan += tmp;
            tmp = __shfl_up(scan, 4, 8); if (g_e >= 4) scan += tmp;
            int run = scan - eqc;
#pragma unroll
            for (int i = 0; i < 8; ++i) {
                int sel = (key[i] > cand) || ((key[i] == cand) && (run < need_eq));
                run += (key[i] == cand);
                mask[i]  = sel ? 1.f : 0.f;
                probs[i] = sel ? 0.03125f : 0.f;
            }
        }

        size_t row = (size_t)(base_t + t) * NEXP + e0;
        *(float4*)&out[row]                = make_float4(probs[0], probs[1], probs[2], probs[3]);
        *(float4*)&out[row + 4]            = make_float4(probs[4], probs[5], probs[6], probs[7]);
        *(float4*)&out[out_pre + row]      = make_float4(pre[0], pre[1], pre[2], pre[3]);
        *(float4*)&out[out_pre + row + 4]  = make_float4(pre[4], pre[5], pre[6], pre[7]);
        *(float4*)&out[out_mask + row]     = make_float4(mask[0], mask[1], mask[2], mask[3]);
        *(float4*)&out[out_mask + row + 4] = make_float4(mask[4], mask[5], mask[6], mask[7]);
    }
}

extern "C" void kernel_launch(void* const* d_in, const int* in_sizes, int n_in,
                              void* d_out, int out_size, void* d_ws, size_t ws_size,
                              hipStream_t stream) {
    (void)in_sizes; (void)n_in; (void)out_size;
    const float* x     = (const float*)d_in[0];
    const float* sim   = (const float*)d_in[1];
    const float* gates = (const float*)d_in[2];
    float* out = (float*)d_out;
    float* ws  = (float*)d_ws;

    hipLaunchKernelGGL(prep_kernel, dim3(1), dim3(256), 0, stream, sim, gates, ws);

    const size_t need = 512 + (size_t)HID * NEXP * sizeof(float);   // prep + wn
    if (ws_size >= need) {
        float* wn = ws + 128;
        hipLaunchKernelGGL(prep2n_kernel, dim3(HID * NEXP / 256), dim3(256), 0, stream,
                           sim, ws, wn);
        hipLaunchKernelGGL(gate_v6_kernel, dim3(N_TOK / 64), dim3(256), 0, stream,
                           x, wn, ws, out);
    } else {
        hipLaunchKernelGGL(gate_kernel_fb, dim3(N_TOK / TOKB), dim3(256), 0, stream,
                           x, sim, ws, out);
    }
}

// Round 7
// 338.066 us; speedup vs baseline: 6.2516x; 6.2516x over previous
//
#include <hip/hip_runtime.h>
#include <math.h>

#define N_TOK   65536
#define HID     1024
#define NEXP    64
#define EPSF    1e-12f

// ---------------- prep: ws[0..63] = 1/||sim col||, ws[64..127] = sigmoid(gates)
__global__ __launch_bounds__(256) void prep_kernel(const float* __restrict__ sim,
                                                   const float* __restrict__ gates,
                                                   float* __restrict__ ws) {
    __shared__ float partial[4][64];
    int e = threadIdx.x & 63;
    int q = threadIdx.x >> 6;   // 0..3
    float s = 0.f;
    for (int h = q * 256; h < q * 256 + 256; ++h) {
        float v = sim[h * NEXP + e];
        s += v * v;
    }
    partial[q][e] = s;
    __syncthreads();
    if (threadIdx.x < 64) {
        float ss = partial[0][e] + partial[1][e] + partial[2][e] + partial[3][e];
        ws[e] = 1.0f / fmaxf(sqrtf(ss), EPSF);
        ws[64 + e] = 1.0f / (1.0f + expf(-gates[e]));
    }
}

// ---------------- prep2: natural-layout normalized W: wn[k*64+e] = sim[k*64+e]*invcol[e]
// (single f32 mul, identical rounding to all passing rounds)
__global__ __launch_bounds__(256) void prep2n_kernel(const float* __restrict__ sim,
                                                     const float* __restrict__ ws_ro,
                                                     float* __restrict__ wn) {
    int idx = blockIdx.x * 256 + threadIdx.x;   // 0..65535
    wn[idx] = sim[idx] * ws_ro[idx & 63];
}

// ---------------- main kernel v7: v6 structure, compiler-chosen registers.
// 256 threads = 4 independent waves, no barriers. Wave handles 16 tokens;
// thread tile 2 tok x 8 exp (16 acc VGPRs).
// x: transposed per-wave LDS tile [2][32 k][16 tok + pad2], ds_read_b64.
// W: VMEM float4 stream (L2-resident normalized copy), depth-2 k prefetch.
// NOTE: no min-waves launch-bounds arg — round 6 showed forcing it caps
// VGPR at 64 and spills the pipeline to scratch (8.4 GB HBM traffic).
__global__ __launch_bounds__(256) void gate_v7_kernel(const float* __restrict__ x,
                                                      const float* __restrict__ wn,
                                                      const float* __restrict__ prep,
                                                      float* __restrict__ out) {
    __shared__ __align__(16) float xs[4][2][32][18];

    const int tid  = threadIdx.x;
    const int lane = tid & 63;
    const int wv   = tid >> 6;               // wave 0..3 (block-uniform per wave)
    const int tg   = lane >> 3;              // token group 0..7 -> tokens 2tg,2tg+1
    const int eg   = lane & 7;               // expert group -> experts eg*8..+7
    const int e0   = eg * 8;
    const int tw   = blockIdx.x * 64 + wv * 16;   // wave's 16-token base
    const int rA   = 2 * tg, rB = rA + 1;         // local token rows

    // staging: lane loads k-quad eg*4..eg*4+3 of rows rA and rB each chunk
    const float* gA = x + (size_t)(tw + rA) * HID + eg * 4;
    const float* gB = x + (size_t)(tw + rB) * HID + eg * 4;

    float acc[2][8];
#pragma unroll
    for (int j = 0; j < 2; ++j)
#pragma unroll
        for (int i = 0; i < 8; ++i) acc[j][i] = 0.f;
    float ssA = 0.f, ssB = 0.f;

    // ---- prologue: stage chunk 0, fuse ss (k-ascending per-lane subsequence)
    {
        float4 fA = *(const float4*)gA;
        float4 fB = *(const float4*)gB;
        const float a[4] = { fA.x, fA.y, fA.z, fA.w };
        const float b[4] = { fB.x, fB.y, fB.z, fB.w };
#pragma unroll
        for (int i = 0; i < 4; ++i) {
            ssA = fmaf(a[i], a[i], ssA);
            ssB = fmaf(b[i], b[i], ssB);
            xs[wv][0][eg * 4 + i][rA] = a[i];
            xs[wv][0][eg * 4 + i][rB] = b[i];
        }
    }

#pragma unroll 1
    for (int c = 0; c < 32; ++c) {
        // issue next chunk's x loads early (consumed after compute)
        float4 nA, nB;
        if (c < 31) {
            nA = *(const float4*)(gA + (c + 1) * 32);
            nB = *(const float4*)(gB + (c + 1) * 32);
        }

        const float (*xb)[18] = xs[wv][c & 1];
        const float* wbase = wn + (size_t)c * 32 * NEXP + e0;

        // W prefetch pipeline, depth 2 k-steps
        float4 a0 = *(const float4*)(wbase);
        float4 b0 = *(const float4*)(wbase + 4);
        float4 a1 = *(const float4*)(wbase + 64);
        float4 b1 = *(const float4*)(wbase + 68);

#pragma unroll 4
        for (int k = 0; k < 32; k += 2) {
            float4 na0, nb0, na1, nb1;
            if (k + 2 < 32) {
                na0 = *(const float4*)(wbase + (k + 2) * 64);
                nb0 = *(const float4*)(wbase + (k + 2) * 64 + 4);
                na1 = *(const float4*)(wbase + (k + 3) * 64);
                nb1 = *(const float4*)(wbase + (k + 3) * 64 + 4);
            }
            const float2 x0 = *(const float2*)&xb[k][rA];
            const float2 x1 = *(const float2*)&xb[k + 1][rA];
            {
                const float w0[8] = { a0.x, a0.y, a0.z, a0.w, b0.x, b0.y, b0.z, b0.w };
#pragma unroll
                for (int i = 0; i < 8; ++i) {
                    acc[0][i] = fmaf(x0.x, w0[i], acc[0][i]);
                    acc[1][i] = fmaf(x0.y, w0[i], acc[1][i]);
                }
            }
            {
                const float w1[8] = { a1.x, a1.y, a1.z, a1.w, b1.x, b1.y, b1.z, b1.w };
#pragma unroll
                for (int i = 0; i < 8; ++i) {
                    acc[0][i] = fmaf(x1.x, w1[i], acc[0][i]);
                    acc[1][i] = fmaf(x1.y, w1[i], acc[1][i]);
                }
            }
            a0 = na0; b0 = nb0; a1 = na1; b1 = nb1;
        }

        // stage chunk c+1 into the other buffer, fuse ss (DS in-order per wave)
        if (c < 31) {
            const int nb_ = (c + 1) & 1;
            const float a[4] = { nA.x, nA.y, nA.z, nA.w };
            const float b[4] = { nB.x, nB.y, nB.z, nB.w };
#pragma unroll
            for (int i = 0; i < 4; ++i) {
                ssA = fmaf(a[i], a[i], ssA);
                ssB = fmaf(b[i], b[i], ssB);
                xs[wv][nb_][eg * 4 + i][rA] = a[i];
                xs[wv][nb_][eg * 4 + i][rB] = b[i];
            }
        }
    }

    // ---- row-norm reduce across the 8 eg lanes of this token group ----
    ssA += __shfl_xor(ssA, 1, 8);
    ssA += __shfl_xor(ssA, 2, 8);
    ssA += __shfl_xor(ssA, 4, 8);
    ssB += __shfl_xor(ssB, 1, 8);
    ssB += __shfl_xor(ssB, 2, 8);
    ssB += __shfl_xor(ssB, 4, 8);
    const float invA = 1.0f / fmaxf(sqrtf(ssA), EPSF);
    const float invB = 1.0f / fmaxf(sqrtf(ssB), EPSF);

    float thr[8];
#pragma unroll
    for (int i = 0; i < 8; ++i) thr[i] = prep[64 + e0 + i];

    const size_t out_pre  = (size_t)N_TOK * NEXP;
    const size_t out_mask = 2 * (size_t)N_TOK * NEXP;

    // ---- epilogue: round-1-proven 8-lane/token path, j over 2 tokens ----
#pragma unroll
    for (int j = 0; j < 2; ++j) {
        const float inv = j ? invB : invA;
        const int t = tw + rA + j;
        float logit[8], pre[8], gated[8];
        int active[8];
        int myact = 0;
#pragma unroll
        for (int i = 0; i < 8; ++i) {
            logit[i] = acc[j][i] * inv;
            pre[i]   = logit[i] - thr[i];
            gated[i] = fmaxf(pre[i], 0.f);
            active[i] = pre[i] > 0.f;
            myact += active[i];
        }
        int rowact = myact;
        rowact += __shfl_xor(rowact, 1, 8);
        rowact += __shfl_xor(rowact, 2, 8);
        rowact += __shfl_xor(rowact, 4, 8);

        float probs[8], mask[8];
        if (rowact > 0) {
            float m = -INFINITY;
#pragma unroll
            for (int i = 0; i < 8; ++i) m = fmaxf(m, active[i] ? gated[i] : -INFINITY);
            m = fmaxf(m, __shfl_xor(m, 1, 8));
            m = fmaxf(m, __shfl_xor(m, 2, 8));
            m = fmaxf(m, __shfl_xor(m, 4, 8));
            float s = 0.f;
#pragma unroll
            for (int i = 0; i < 8; ++i) {
                float ev = active[i] ? expf(gated[i] - m) : 0.f;
                probs[i] = ev; s += ev;
            }
            s += __shfl_xor(s, 1, 8);
            s += __shfl_xor(s, 2, 8);
            s += __shfl_xor(s, 4, 8);
            float rs = 1.0f / s;
#pragma unroll
            for (int i = 0; i < 8; ++i) {
                probs[i] *= rs;
                mask[i] = active[i] ? 1.f : 0.f;
            }
        } else {
            // top-32 fallback: exact 32nd-largest via radix descent on order keys
            unsigned key[8];
#pragma unroll
            for (int i = 0; i < 8; ++i) {
                unsigned u = __float_as_uint(logit[i]);
                key[i] = (u & 0x80000000u) ? ~u : (u | 0x80000000u);
            }
            unsigned cand = 0u;
            for (int bit = 31; bit >= 0; --bit) {
                unsigned test = cand | (1u << bit);
                int c = 0;
#pragma unroll
                for (int i = 0; i < 8; ++i) c += (key[i] >= test);
                c += __shfl_xor(c, 1, 8);
                c += __shfl_xor(c, 2, 8);
                c += __shfl_xor(c, 4, 8);
                if (c >= 32) cand = test;
            }
            int cgt = 0;
#pragma unroll
            for (int i = 0; i < 8; ++i) cgt += (key[i] > cand);
            cgt += __shfl_xor(cgt, 1, 8);
            cgt += __shfl_xor(cgt, 2, 8);
            cgt += __shfl_xor(cgt, 4, 8);
            int need_eq = 32 - cgt;

            int eqc = 0;
#pragma unroll
            for (int i = 0; i < 8; ++i) eqc += (key[i] == cand);
            int scan = eqc, tmp;
            tmp = __shfl_up(scan, 1, 8); if (eg >= 1) scan += tmp;
            tmp = __shfl_up(scan, 2, 8); if (eg >= 2) scan += tmp;
            tmp = __shfl_up(scan, 4, 8); if (eg >= 4) scan += tmp;
            int run = scan - eqc;   // ties with smaller global index
#pragma unroll
            for (int i = 0; i < 8; ++i) {
                int sel = (key[i] > cand) || ((key[i] == cand) && (run < need_eq));
                run += (key[i] == cand);
                mask[i]  = sel ? 1.f : 0.f;
                probs[i] = sel ? 0.03125f : 0.f;   // gated==0 on fallback rows
            }
        }

        const size_t row = (size_t)t * NEXP + e0;
        *(float4*)&out[row]                = make_float4(probs[0], probs[1], probs[2], probs[3]);
        *(float4*)&out[row + 4]            = make_float4(probs[4], probs[5], probs[6], probs[7]);
        *(float4*)&out[out_pre + row]      = make_float4(pre[0], pre[1], pre[2], pre[3]);
        *(float4*)&out[out_pre + row + 4]  = make_float4(pre[4], pre[5], pre[6], pre[7]);
        *(float4*)&out[out_mask + row]     = make_float4(mask[0], mask[1], mask[2], mask[3]);
        *(float4*)&out[out_mask + row + 4] = make_float4(mask[4], mask[5], mask[6], mask[7]);
    }
}

// ---------------- fallback (verbatim round-1 kernel, used only if ws too small)
#define TOKB    128
#define KC      64
#define XPAD    65

__global__ __launch_bounds__(256) void gate_kernel_fb(const float* __restrict__ x,
                                                      const float* __restrict__ sim,
                                                      const float* __restrict__ prep,
                                                      float* __restrict__ out) {
    __shared__ float x_lds[TOKB][XPAD];
    __shared__ float w_lds[KC][NEXP];
    __shared__ float ss_lds[TOKB];
    __shared__ float invcol[NEXP];
    __shared__ float thr_s[NEXP];

    const int tid = threadIdx.x;
    const int base_t = blockIdx.x * TOKB;

    if (tid < NEXP) { invcol[tid] = prep[tid]; thr_s[tid] = prep[64 + tid]; }
    if (tid < TOKB) ss_lds[tid] = 0.f;

    const int g_e = tid & 7;
    const int g_t = tid >> 3;
    const int e0 = g_e * 8;
    const int t0 = g_t * 4;

    const int lt = tid >> 4;
    const int lk = (tid & 15) * 4;

    float acc[4][8];
#pragma unroll
    for (int j = 0; j < 4; ++j)
#pragma unroll
        for (int i = 0; i < 8; ++i) acc[j][i] = 0.f;

    for (int kc = 0; kc < HID; kc += KC) {
        __syncthreads();
#pragma unroll
        for (int it = 0; it < 4; ++it) {
            int flat4 = it * 256 + tid;
            int k = flat4 >> 4;
            int e = (flat4 & 15) * 4;
            float4 v = *(const float4*)&sim[(size_t)(kc + k) * NEXP + e];
            v.x *= invcol[e]; v.y *= invcol[e + 1]; v.z *= invcol[e + 2]; v.w *= invcol[e + 3];
            *(float4*)&w_lds[k][e] = v;
        }
#pragma unroll
        for (int it = 0; it < 8; ++it) {
            int t = it * 16 + lt;
            float4 v = *(const float4*)&x[(size_t)(base_t + t) * HID + kc + lk];
            x_lds[t][lk + 0] = v.x; x_lds[t][lk + 1] = v.y;
            x_lds[t][lk + 2] = v.z; x_lds[t][lk + 3] = v.w;
            float s4 = v.x * v.x + v.y * v.y + v.z * v.z + v.w * v.w;
            s4 += __shfl_xor(s4, 1, 16);
            s4 += __shfl_xor(s4, 2, 16);
            s4 += __shfl_xor(s4, 4, 16);
            s4 += __shfl_xor(s4, 8, 16);
            if ((tid & 15) == 0) ss_lds[t] += s4;
        }
        __syncthreads();
#pragma unroll 8
        for (int k = 0; k < KC; ++k) {
            float x0 = x_lds[t0 + 0][k];
            float x1 = x_lds[t0 + 1][k];
            float x2 = x_lds[t0 + 2][k];
            float x3 = x_lds[t0 + 3][k];
            float4 w0 = *(const float4*)&w_lds[k][e0];
            float4 w1 = *(const float4*)&w_lds[k][e0 + 4];
            float wv[8] = { w0.x, w0.y, w0.z, w0.w, w1.x, w1.y, w1.z, w1.w };
#pragma unroll
            for (int i = 0; i < 8; ++i) {
                acc[0][i] += x0 * wv[i];
                acc[1][i] += x1 * wv[i];
                acc[2][i] += x2 * wv[i];
                acc[3][i] += x3 * wv[i];
            }
        }
    }

    const size_t out_pre  = (size_t)N_TOK * NEXP;
    const size_t out_mask = 2 * (size_t)N_TOK * NEXP;

#pragma unroll
    for (int j = 0; j < 4; ++j) {
        int t = t0 + j;
        float inv = 1.0f / fmaxf(sqrtf(ss_lds[t]), EPSF);
        float logit[8], pre[8], gated[8];
        int active[8];
        int myact = 0;
#pragma unroll
        for (int i = 0; i < 8; ++i) {
            logit[i] = acc[j][i] * inv;
            pre[i]   = logit[i] - thr_s[e0 + i];
            gated[i] = fmaxf(pre[i], 0.f);
            active[i] = pre[i] > 0.f;
            myact += active[i];
        }
        int rowact = myact;
        rowact += __shfl_xor(rowact, 1, 8);
        rowact += __shfl_xor(rowact, 2, 8);
        rowact += __shfl_xor(rowact, 4, 8);

        float probs[8], mask[8];
        if (rowact > 0) {
            float m = -INFINITY;
#pragma unroll
            for (int i = 0; i < 8; ++i) m = fmaxf(m, active[i] ? gated[i] : -INFINITY);
            m = fmaxf(m, __shfl_xor(m, 1, 8));
            m = fmaxf(m, __shfl_xor(m, 2, 8));
            m = fmaxf(m, __shfl_xor(m, 4, 8));
            float s = 0.f;
#pragma unroll
            for (int i = 0; i < 8; ++i) {
                float ev = active[i] ? expf(gated[i] - m) : 0.f;
                probs[i] = ev; s += ev;
            }
            s += __shfl_xor(s, 1, 8);
            s += __shfl_xor(s, 2, 8);
            s += __shfl_xor(s, 4, 8);
            float rs = 1.0f / s;
#pragma unroll
            for (int i = 0; i < 8; ++i) {
                probs[i] *= rs;
                mask[i] = active[i] ? 1.f : 0.f;
            }
        } else {
            unsigned key[8];
#pragma unroll
            for (int i = 0; i < 8; ++i) {
                unsigned u = __float_as_uint(logit[i]);
                key[i] = (u & 0x80000000u) ? ~u : (u | 0x80000000u);
            }
            unsigned cand = 0u;
            for (int bit = 31; bit >= 0; --bit) {
                unsigned test = cand | (1u << bit);
                int c = 0;
#pragma unroll
                for (int i = 0; i < 8; ++i) c += (key[i] >= test);
                c += __shfl_xor(c, 1, 8);
                c += __shfl_xor(c, 2, 8);
                c += __shfl_xor(c, 4, 8);
                if (c >= 32) cand = test;
            }
            int cgt = 0;
#pragma unroll
            for (int i = 0; i < 8; ++i) cgt += (key[i] > cand);
            cgt += __shfl_xor(cgt, 1, 8);
            cgt += __shfl_xor(cgt, 2, 8);
            cgt += __shfl_xor(cgt, 4, 8);
            int need_eq = 32 - cgt;

            int eqc = 0;
#pragma unroll
            for (int i = 0; i < 8; ++i) eqc += (key[i] == cand);
            int scan = eqc, tmp;
            tmp = __shfl_up(scan, 1, 8); if (g_e >= 1) scan += tmp;
            tmp = __shfl_up(scan, 2, 8); if (g_e >= 2) scan += tmp;
            tmp = __shfl_up(scan, 4, 8); if (g_e >= 4) scan += tmp;
            int run = scan - eqc;
#pragma unroll
            for (int i = 0; i < 8; ++i) {
                int sel = (key[i] > cand) || ((key[i] == cand) && (run < need_eq));
                run += (key[i] == cand);
                mask[i]  = sel ? 1.f : 0.f;
                probs[i] = sel ? 0.03125f : 0.f;
            }
        }

        size_t row = (size_t)(base_t + t) * NEXP + e0;
        *(float4*)&out[row]                = make_float4(probs[0], probs[1], probs[2], probs[3]);
        *(float4*)&out[row + 4]            = make_float4(probs[4], probs[5], probs[6], probs[7]);
        *(float4*)&out[out_pre + row]      = make_float4(pre[0], pre[1], pre[2], pre[3]);
        *(float4*)&out[out_pre + row + 4]  = make_float4(pre[4], pre[5], pre[6], pre[7]);
        *(float4*)&out[out_mask + row]     = make_float4(mask[0], mask[1], mask[2], mask[3]);
        *(float4*)&out[out_mask + row + 4] = make_float4(mask[4], mask[5], mask[6], mask[7]);
    }
}

extern "C" void kernel_launch(void* const* d_in, const int* in_sizes, int n_in,
                              void* d_out, int out_size, void* d_ws, size_t ws_size,
                              hipStream_t stream) {
    (void)in_sizes; (void)n_in; (void)out_size;
    const float* x     = (const float*)d_in[0];
    const float* sim   = (const float*)d_in[1];
    const float* gates = (const float*)d_in[2];
    float* out = (float*)d_out;
    float* ws  = (float*)d_ws;

    hipLaunchKernelGGL(prep_kernel, dim3(1), dim3(256), 0, stream, sim, gates, ws);

    const size_t need = 512 + (size_t)HID * NEXP * sizeof(float);   // prep + wn
    if (ws_size >= need) {
        float* wn = ws + 128;
        hipLaunchKernelGGL(prep2n_kernel, dim3(HID * NEXP / 256), dim3(256), 0, stream,
                           sim, ws, wn);
        hipLaunchKernelGGL(gate_v7_kernel, dim3(N_TOK / 64), dim3(256), 0, stream,
                           x, wn, ws, out);
    } else {
        hipLaunchKernelGGL(gate_kernel_fb, dim3(N_TOK / TOKB), dim3(256), 0, stream,
                           x, sim, ws, out);
    }
}

// Round 8
// 183.621 us; speedup vs baseline: 11.5099x; 1.8411x over previous
//
#include <hip/hip_runtime.h>
#include <math.h>

#define N_TOK   65536
#define HID     1024
#define NEXP    64
#define EPSF    1e-12f

// ---------------- prep: ws[0..63] = 1/||sim col||, ws[64..127] = sigmoid(gates)
__global__ __launch_bounds__(256) void prep_kernel(const float* __restrict__ sim,
                                                   const float* __restrict__ gates,
                                                   float* __restrict__ ws) {
    __shared__ float partial[4][64];
    int e = threadIdx.x & 63;
    int q = threadIdx.x >> 6;   // 0..3
    float s = 0.f;
    for (int h = q * 256; h < q * 256 + 256; ++h) {
        float v = sim[h * NEXP + e];
        s += v * v;
    }
    partial[q][e] = s;
    __syncthreads();
    if (threadIdx.x < 64) {
        float ss = partial[0][e] + partial[1][e] + partial[2][e] + partial[3][e];
        ws[e] = 1.0f / fmaxf(sqrtf(ss), EPSF);
        ws[64 + e] = 1.0f / (1.0f + expf(-gates[e]));
    }
}

// ---------------- prep2: natural-layout normalized W: wn[k*64+e] = sim[k*64+e]*invcol[e]
__global__ __launch_bounds__(256) void prep2n_kernel(const float* __restrict__ sim,
                                                     const float* __restrict__ ws_ro,
                                                     float* __restrict__ wn) {
    int idx = blockIdx.x * 256 + threadIdx.x;   // 0..65535
    wn[idx] = sim[idx] * ws_ro[idx & 63];
}

// ---------------- main kernel v8: 128 threads = 2 waves, K-split by 2.
// Both waves own the SAME 64 tokens; wave w computes k in [w*512, w*512+512)
// with the round-5-proven inner loop (T=8 tok x 8 exp, double-buffered
// transposed x LDS tile, depth-2 VMEM W prefetch). Partials combined in LDS
// (2 barriers), then round-1-proven 8-lane/token epilogue on both waves.
// NOTE: no min-waves launch-bounds arg (round 6: forcing it spills to scratch).
__global__ __launch_bounds__(128) void gate_v8_kernel(const float* __restrict__ x,
                                                      const float* __restrict__ wn,
                                                      const float* __restrict__ prep,
                                                      float* __restrict__ out) {
    // smem floats:
    //  [0..8703]   xs: wave w at w*4352, layout [2 buf][32 k][68 tok+pad]
    //  overlay after GEMM: logits_l[64][68] at 0 (wave0 region),
    //                      plane[64][64]   at 4352 (wave1 region)
    //  [8704..8831] ss_part[2][64]
    __shared__ __align__(16) float smem[8832];
    float* ss_part = smem + 8704;

    const int tid  = threadIdx.x;
    const int lane = tid & 63;
    const int wv   = tid >> 6;            // 0..1 (k-half)
    const int tg   = lane >> 3;           // token group 0..7
    const int eg   = lane & 7;            // expert group
    const int e0   = eg * 8;
    const int tbase = blockIdx.x * 64;
    const int kbase = wv * 512;

    float* xsw = smem + wv * 4352;        // this wave's [2][32][68] tile

    // staging: lane stages its own token row (k-range of this wave)
    const float4* xq4 = (const float4*)(x + (size_t)(tbase + lane) * HID + kbase);

    float acc[8][8];
#pragma unroll
    for (int t = 0; t < 8; ++t)
#pragma unroll
        for (int e = 0; e < 8; ++e) acc[t][e] = 0.f;
    float ss = 0.f;

    // ---- prologue: stage chunk 0, fuse ss (k-ascending within this half)
    {
        float4 st[8];
#pragma unroll
        for (int q = 0; q < 8; ++q) st[q] = xq4[q];
#pragma unroll
        for (int q = 0; q < 8; ++q) {
            ss = fmaf(st[q].x, st[q].x, ss);
            ss = fmaf(st[q].y, st[q].y, ss);
            ss = fmaf(st[q].z, st[q].z, ss);
            ss = fmaf(st[q].w, st[q].w, ss);
            xsw[(q * 4 + 0) * 68 + lane] = st[q].x;
            xsw[(q * 4 + 1) * 68 + lane] = st[q].y;
            xsw[(q * 4 + 2) * 68 + lane] = st[q].z;
            xsw[(q * 4 + 3) * 68 + lane] = st[q].w;
        }
    }

#define FMA8x8(XA, XB, WA, WB)                                              \
    do {                                                                    \
        const float xv_[8] = { XA.x, XA.y, XA.z, XA.w, XB.x, XB.y, XB.z, XB.w }; \
        const float wv_[8] = { WA.x, WA.y, WA.z, WA.w, WB.x, WB.y, WB.z, WB.w }; \
        _Pragma("unroll")                                                   \
        for (int t_ = 0; t_ < 8; ++t_)                                      \
            _Pragma("unroll")                                               \
            for (int e_ = 0; e_ < 8; ++e_)                                  \
                acc[t_][e_] = fmaf(xv_[t_], wv_[e_], acc[t_][e_]);          \
    } while (0)

#pragma unroll 1
    for (int c = 0; c < 16; ++c) {
        // issue next chunk's x loads early (consumed after compute)
        float4 st[8];
        if (c < 15) {
#pragma unroll
            for (int q = 0; q < 8; ++q) st[q] = xq4[(c + 1) * 8 + q];
        }

        const float* xb = xsw + (c & 1) * 2176;
        const float* wbase = wn + (size_t)(kbase + c * 32) * NEXP + e0;

        // W prefetch pipeline, depth 2 k-steps
        float4 a0 = *(const float4*)(wbase);
        float4 b0 = *(const float4*)(wbase + 4);
        float4 a1 = *(const float4*)(wbase + 64);
        float4 b1 = *(const float4*)(wbase + 68);

#pragma unroll 4
        for (int k = 0; k < 32; k += 2) {
            float4 na0, nb0, na1, nb1;
            if (k + 2 < 32) {
                na0 = *(const float4*)(wbase + (k + 2) * 64);
                nb0 = *(const float4*)(wbase + (k + 2) * 64 + 4);
                na1 = *(const float4*)(wbase + (k + 3) * 64);
                nb1 = *(const float4*)(wbase + (k + 3) * 64 + 4);
            }
            const float4 xa0 = *(const float4*)&xb[k * 68 + tg * 8];
            const float4 xb0 = *(const float4*)&xb[k * 68 + tg * 8 + 4];
            const float4 xa1 = *(const float4*)&xb[(k + 1) * 68 + tg * 8];
            const float4 xb1 = *(const float4*)&xb[(k + 1) * 68 + tg * 8 + 4];
            FMA8x8(xa0, xb0, a0, b0);
            FMA8x8(xa1, xb1, a1, b1);
            a0 = na0; b0 = nb0; a1 = na1; b1 = nb1;
        }

        // stage chunk c+1 into the other buffer, fuse ss
        if (c < 15) {
            float* xn = xsw + ((c + 1) & 1) * 2176;
#pragma unroll
            for (int q = 0; q < 8; ++q) {
                ss = fmaf(st[q].x, st[q].x, ss);
                ss = fmaf(st[q].y, st[q].y, ss);
                ss = fmaf(st[q].z, st[q].z, ss);
                ss = fmaf(st[q].w, st[q].w, ss);
                xn[(q * 4 + 0) * 68 + lane] = st[q].x;
                xn[(q * 4 + 1) * 68 + lane] = st[q].y;
                xn[(q * 4 + 2) * 68 + lane] = st[q].z;
                xn[(q * 4 + 3) * 68 + lane] = st[q].w;
            }
        }
    }
#undef FMA8x8

    // ---- combine the two k-half partials ----
    ss_part[wv * 64 + lane] = ss;         // partial row-norm (own token)

    if (wv == 1) {
        // wave1 dumps its partial plane into its own (finished) xs region
        float* plane = smem + 4352;
#pragma unroll
        for (int j = 0; j < 8; ++j) {
            float* p = &plane[(tg * 8 + j) * 64 + e0];
            *(float4*)(p)     = make_float4(acc[j][0], acc[j][1], acc[j][2], acc[j][3]);
            *(float4*)(p + 4) = make_float4(acc[j][4], acc[j][5], acc[j][6], acc[j][7]);
        }
    }
    __syncthreads();

    if (wv == 0) {
        // wave0 adds (low-k + high-k, ascending block order) and writes logits
        const float* plane = smem + 4352;
#pragma unroll
        for (int j = 0; j < 8; ++j) {
            const float* p = &plane[(tg * 8 + j) * 64 + e0];
            float4 p0 = *(const float4*)(p);
            float4 p1 = *(const float4*)(p + 4);
            acc[j][0] += p0.x; acc[j][1] += p0.y; acc[j][2] += p0.z; acc[j][3] += p0.w;
            acc[j][4] += p1.x; acc[j][5] += p1.y; acc[j][6] += p1.z; acc[j][7] += p1.w;
            float* lg = &smem[(tg * 8 + j) * 68 + e0];   // logits_l stride 68
            *(float4*)(lg)     = make_float4(acc[j][0], acc[j][1], acc[j][2], acc[j][3]);
            *(float4*)(lg + 4) = make_float4(acc[j][4], acc[j][5], acc[j][6], acc[j][7]);
        }
    }
    __syncthreads();

    // ---- epilogue: both waves, 8 lanes per token, 4 tokens per lane-group ----
    float thr[8];
#pragma unroll
    for (int i = 0; i < 8; ++i) thr[i] = prep[64 + e0 + i];

    const size_t out_pre  = (size_t)N_TOK * NEXP;
    const size_t out_mask = 2 * (size_t)N_TOK * NEXP;

#pragma unroll
    for (int j = 0; j < 4; ++j) {
        const int tl = wv * 32 + tg * 4 + j;          // local token 0..63
        const int t  = tbase + tl;
        const float sst = ss_part[tl] + ss_part[64 + tl];
        const float inv = 1.0f / fmaxf(sqrtf(sst), EPSF);

        float4 l0 = *(const float4*)&smem[tl * 68 + e0];
        float4 l1 = *(const float4*)&smem[tl * 68 + e0 + 4];
        float logit[8] = { l0.x * inv, l0.y * inv, l0.z * inv, l0.w * inv,
                           l1.x * inv, l1.y * inv, l1.z * inv, l1.w * inv };
        float pre[8], gated[8];
        int active[8];
        int myact = 0;
#pragma unroll
        for (int i = 0; i < 8; ++i) {
            pre[i]   = logit[i] - thr[i];
            gated[i] = fmaxf(pre[i], 0.f);
            active[i] = pre[i] > 0.f;
            myact += active[i];
        }
        int rowact = myact;
        rowact += __shfl_xor(rowact, 1, 8);
        rowact += __shfl_xor(rowact, 2, 8);
        rowact += __shfl_xor(rowact, 4, 8);

        float probs[8], mask[8];
        if (rowact > 0) {
            float m = -INFINITY;
#pragma unroll
            for (int i = 0; i < 8; ++i) m = fmaxf(m, active[i] ? gated[i] : -INFINITY);
            m = fmaxf(m, __shfl_xor(m, 1, 8));
            m = fmaxf(m, __shfl_xor(m, 2, 8));
            m = fmaxf(m, __shfl_xor(m, 4, 8));
            float s = 0.f;
#pragma unroll
            for (int i = 0; i < 8; ++i) {
                float ev = active[i] ? expf(gated[i] - m) : 0.f;
                probs[i] = ev; s += ev;
            }
            s += __shfl_xor(s, 1, 8);
            s += __shfl_xor(s, 2, 8);
            s += __shfl_xor(s, 4, 8);
            float rs = 1.0f / s;
#pragma unroll
            for (int i = 0; i < 8; ++i) {
                probs[i] *= rs;
                mask[i] = active[i] ? 1.f : 0.f;
            }
        } else {
            // top-32 fallback: exact 32nd-largest via radix descent on order keys
            unsigned key[8];
#pragma unroll
            for (int i = 0; i < 8; ++i) {
                unsigned u = __float_as_uint(logit[i]);
                key[i] = (u & 0x80000000u) ? ~u : (u | 0x80000000u);
            }
            unsigned cand = 0u;
            for (int bit = 31; bit >= 0; --bit) {
                unsigned test = cand | (1u << bit);
                int c = 0;
#pragma unroll
                for (int i = 0; i < 8; ++i) c += (key[i] >= test);
                c += __shfl_xor(c, 1, 8);
                c += __shfl_xor(c, 2, 8);
                c += __shfl_xor(c, 4, 8);
                if (c >= 32) cand = test;
            }
            int cgt = 0;
#pragma unroll
            for (int i = 0; i < 8; ++i) cgt += (key[i] > cand);
            cgt += __shfl_xor(cgt, 1, 8);
            cgt += __shfl_xor(cgt, 2, 8);
            cgt += __shfl_xor(cgt, 4, 8);
            int need_eq = 32 - cgt;

            int eqc = 0;
#pragma unroll
            for (int i = 0; i < 8; ++i) eqc += (key[i] == cand);
            int scan = eqc, tmp;
            tmp = __shfl_up(scan, 1, 8); if (eg >= 1) scan += tmp;
            tmp = __shfl_up(scan, 2, 8); if (eg >= 2) scan += tmp;
            tmp = __shfl_up(scan, 4, 8); if (eg >= 4) scan += tmp;
            int run = scan - eqc;   // ties with smaller global index
#pragma unroll
            for (int i = 0; i < 8; ++i) {
                int sel = (key[i] > cand) || ((key[i] == cand) && (run < need_eq));
                run += (key[i] == cand);
                mask[i]  = sel ? 1.f : 0.f;
                probs[i] = sel ? 0.03125f : 0.f;   // gated==0 on fallback rows
            }
        }

        const size_t row = (size_t)t * NEXP + e0;
        *(float4*)&out[row]                = make_float4(probs[0], probs[1], probs[2], probs[3]);
        *(float4*)&out[row + 4]            = make_float4(probs[4], probs[5], probs[6], probs[7]);
        *(float4*)&out[out_pre + row]      = make_float4(pre[0], pre[1], pre[2], pre[3]);
        *(float4*)&out[out_pre + row + 4]  = make_float4(pre[4], pre[5], pre[6], pre[7]);
        *(float4*)&out[out_mask + row]     = make_float4(mask[0], mask[1], mask[2], mask[3]);
        *(float4*)&out[out_mask + row + 4] = make_float4(mask[4], mask[5], mask[6], mask[7]);
    }
}

// ---------------- fallback (verbatim round-1 kernel, used only if ws too small)
#define TOKB    128
#define KC      64
#define XPAD    65

__global__ __launch_bounds__(256) void gate_kernel_fb(const float* __restrict__ x,
                                                      const float* __restrict__ sim,
                                                      const float* __restrict__ prep,
                                                      float* __restrict__ out) {
    __shared__ float x_lds[TOKB][XPAD];
    __shared__ float w_lds[KC][NEXP];
    __shared__ float ss_lds[TOKB];
    __shared__ float invcol[NEXP];
    __shared__ float thr_s[NEXP];

    const int tid = threadIdx.x;
    const int base_t = blockIdx.x * TOKB;

    if (tid < NEXP) { invcol[tid] = prep[tid]; thr_s[tid] = prep[64 + tid]; }
    if (tid < TOKB) ss_lds[tid] = 0.f;

    const int g_e = tid & 7;
    const int g_t = tid >> 3;
    const int e0 = g_e * 8;
    const int t0 = g_t * 4;

    const int lt = tid >> 4;
    const int lk = (tid & 15) * 4;

    float acc[4][8];
#pragma unroll
    for (int j = 0; j < 4; ++j)
#pragma unroll
        for (int i = 0; i < 8; ++i) acc[j][i] = 0.f;

    for (int kc = 0; kc < HID; kc += KC) {
        __syncthreads();
#pragma unroll
        for (int it = 0; it < 4; ++it) {
            int flat4 = it * 256 + tid;
            int k = flat4 >> 4;
            int e = (flat4 & 15) * 4;
            float4 v = *(const float4*)&sim[(size_t)(kc + k) * NEXP + e];
            v.x *= invcol[e]; v.y *= invcol[e + 1]; v.z *= invcol[e + 2]; v.w *= invcol[e + 3];
            *(float4*)&w_lds[k][e] = v;
        }
#pragma unroll
        for (int it = 0; it < 8; ++it) {
            int t = it * 16 + lt;
            float4 v = *(const float4*)&x[(size_t)(base_t + t) * HID + kc + lk];
            x_lds[t][lk + 0] = v.x; x_lds[t][lk + 1] = v.y;
            x_lds[t][lk + 2] = v.z; x_lds[t][lk + 3] = v.w;
            float s4 = v.x * v.x + v.y * v.y + v.z * v.z + v.w * v.w;
            s4 += __shfl_xor(s4, 1, 16);
            s4 += __shfl_xor(s4, 2, 16);
            s4 += __shfl_xor(s4, 4, 16);
            s4 += __shfl_xor(s4, 8, 16);
            if ((tid & 15) == 0) ss_lds[t] += s4;
        }
        __syncthreads();
#pragma unroll 8
        for (int k = 0; k < KC; ++k) {
            float x0 = x_lds[t0 + 0][k];
            float x1 = x_lds[t0 + 1][k];
            float x2 = x_lds[t0 + 2][k];
            float x3 = x_lds[t0 + 3][k];
            float4 w0 = *(const float4*)&w_lds[k][e0];
            float4 w1 = *(const float4*)&w_lds[k][e0 + 4];
            float wv[8] = { w0.x, w0.y, w0.z, w0.w, w1.x, w1.y, w1.z, w1.w };
#pragma unroll
            for (int i = 0; i < 8; ++i) {
                acc[0][i] += x0 * wv[i];
                acc[1][i] += x1 * wv[i];
                acc[2][i] += x2 * wv[i];
                acc[3][i] += x3 * wv[i];
            }
        }
    }

    const size_t out_pre  = (size_t)N_TOK * NEXP;
    const size_t out_mask = 2 * (size_t)N_TOK * NEXP;

#pragma unroll
    for (int j = 0; j < 4; ++j) {
        int t = t0 + j;
        float inv = 1.0f / fmaxf(sqrtf(ss_lds[t]), EPSF);
        float logit[8], pre[8], gated[8];
        int active[8];
        int myact = 0;
#pragma unroll
        for (int i = 0; i < 8; ++i) {
            logit[i] = acc[j][i] * inv;
            pre[i]   = logit[i] - thr_s[e0 + i];
            gated[i] = fmaxf(pre[i], 0.f);
            active[i] = pre[i] > 0.f;
            myact += active[i];
        }
        int rowact = myact;
        rowact += __shfl_xor(rowact, 1, 8);
        rowact += __shfl_xor(rowact, 2, 8);
        rowact += __shfl_xor(rowact, 4, 8);

        float probs[8], mask[8];
        if (rowact > 0) {
            float m = -INFINITY;
#pragma unroll
            for (int i = 0; i < 8; ++i) m = fmaxf(m, active[i] ? gated[i] : -INFINITY);
            m = fmaxf(m, __shfl_xor(m, 1, 8));
            m = fmaxf(m, __shfl_xor(m, 2, 8));
            m = fmaxf(m, __shfl_xor(m, 4, 8));
            float s = 0.f;
#pragma unroll
            for (int i = 0; i < 8; ++i) {
                float ev = active[i] ? expf(gated[i] - m) : 0.f;
                probs[i] = ev; s += ev;
            }
            s += __shfl_xor(s, 1, 8);
            s += __shfl_xor(s, 2, 8);
            s += __shfl_xor(s, 4, 8);
            float rs = 1.0f / s;
#pragma unroll
            for (int i = 0; i < 8; ++i) {
                probs[i] *= rs;
                mask[i] = active[i] ? 1.f : 0.f;
            }
        } else {
            unsigned key[8];
#pragma unroll
            for (int i = 0; i < 8; ++i) {
                unsigned u = __float_as_uint(logit[i]);
                key[i] = (u & 0x80000000u) ? ~u : (u | 0x80000000u);
            }
            unsigned cand = 0u;
            for (int bit = 31; bit >= 0; --bit) {
                unsigned test = cand | (1u << bit);
                int c = 0;
#pragma unroll
                for (int i = 0; i < 8; ++i) c += (key[i] >= test);
                c += __shfl_xor(c, 1, 8);
                c += __shfl_xor(c, 2, 8);
                c += __shfl_xor(c, 4, 8);
                if (c >= 32) cand = test;
            }
            int cgt = 0;
#pragma unroll
            for (int i = 0; i < 8; ++i) cgt += (key[i] > cand);
            cgt += __shfl_xor(cgt, 1, 8);
            cgt += __shfl_xor(cgt, 2, 8);
            cgt += __shfl_xor(cgt, 4, 8);
            int need_eq = 32 - cgt;

            int eqc = 0;
#pragma unroll
            for (int i = 0; i < 8; ++i) eqc += (key[i] == cand);
            int scan = eqc, tmp;
            tmp = __shfl_up(scan, 1, 8); if (g_e >= 1) scan += tmp;
            tmp = __shfl_up(scan, 2, 8); if (g_e >= 2) scan += tmp;
            tmp = __shfl_up(scan, 4, 8); if (g_e >= 4) scan += tmp;
            int run = scan - eqc;
#pragma unroll
            for (int i = 0; i < 8; ++i) {
                int sel = (key[i] > cand) || ((key[i] == cand) && (run < need_eq));
                run += (key[i] == cand);
                mask[i]  = sel ? 1.f : 0.f;
                probs[i] = sel ? 0.03125f : 0.f;
            }
        }

        size_t row = (size_t)(base_t + t) * NEXP + e0;
        *(float4*)&out[row]                = make_float4(probs[0], probs[1], probs[2], probs[3]);
        *(float4*)&out[row + 4]            = make_float4(probs[4], probs[5], probs[6], probs[7]);
        *(float4*)&out[out_pre + row]      = make_float4(pre[0], pre[1], pre[2], pre[3]);
        *(float4*)&out[out_pre + row + 4]  = make_float4(pre[4], pre[5], pre[6], pre[7]);
        *(float4*)&out[out_mask + row]     = make_float4(mask[0], mask[1], mask[2], mask[3]);
        *(float4*)&out[out_mask + row + 4] = make_float4(mask[4], mask[5], mask[6], mask[7]);
    }
}

extern "C" void kernel_launch(void* const* d_in, const int* in_sizes, int n_in,
                              void* d_out, int out_size, void* d_ws, size_t ws_size,
                              hipStream_t stream) {
    (void)in_sizes; (void)n_in; (void)out_size;
    const float* x     = (const float*)d_in[0];
    const float* sim   = (const float*)d_in[1];
    const float* gates = (const float*)d_in[2];
    float* out = (float*)d_out;
    float* ws  = (float*)d_ws;

    hipLaunchKernelGGL(prep_kernel, dim3(1), dim3(256), 0, stream, sim, gates, ws);

    const size_t need = 512 + (size_t)HID * NEXP * sizeof(float);   // prep + wn
    if (ws_size >= need) {
        float* wn = ws + 128;
        hipLaunchKernelGGL(prep2n_kernel, dim3(HID * NEXP / 256), dim3(256), 0, stream,
                           sim, ws, wn);
        hipLaunchKernelGGL(gate_v8_kernel, dim3(N_TOK / 64), dim3(128), 0, stream,
                           x, wn, ws, out);
    } else {
        hipLaunchKernelGGL(gate_kernel_fb, dim3(N_TOK / TOKB), dim3(256), 0, stream,
                           x, sim, ws, out);
    }
}

// Round 9
// 174.711 us; speedup vs baseline: 12.0969x; 1.0510x over previous
//
#include <hip/hip_runtime.h>
#include <math.h>

#define N_TOK   65536
#define HID     1024
#define NEXP    64
#define EPSF    1e-12f

// ---------------- prep: ws[0..63] = 1/||sim col||, ws[64..127] = sigmoid(gates)
__global__ __launch_bounds__(256) void prep_kernel(const float* __restrict__ sim,
                                                   const float* __restrict__ gates,
                                                   float* __restrict__ ws) {
    __shared__ float partial[4][64];
    int e = threadIdx.x & 63;
    int q = threadIdx.x >> 6;   // 0..3
    float s = 0.f;
    for (int h = q * 256; h < q * 256 + 256; ++h) {
        float v = sim[h * NEXP + e];
        s += v * v;
    }
    partial[q][e] = s;
    __syncthreads();
    if (threadIdx.x < 64) {
        float ss = partial[0][e] + partial[1][e] + partial[2][e] + partial[3][e];
        ws[e] = 1.0f / fmaxf(sqrtf(ss), EPSF);
        ws[64 + e] = 1.0f / (1.0f + expf(-gates[e]));
    }
}

// ---------------- prep2: natural-layout normalized W: wn[k*64+e] = sim[k*64+e]*invcol[e]
__global__ __launch_bounds__(256) void prep2n_kernel(const float* __restrict__ sim,
                                                     const float* __restrict__ ws_ro,
                                                     float* __restrict__ wn) {
    int idx = blockIdx.x * 256 + threadIdx.x;   // 0..65535
    wn[idx] = sim[idx] * ws_ro[idx & 63];
}

// ---------------- main kernel v9: 256 threads = 4 waves, K-split by 4.
// All waves own the SAME 64 tokens; wave w computes k in [w*256, w*256+256)
// with the proven T=8x8 inner loop (double-buffered transposed x LDS tile,
// chunk=16 k, depth-2 VMEM W prefetch). Partials combined via plane overlay
// in xs (3 barriers), epilogue split 16 tokens/wave.
// NOTE: no min-waves launch-bounds arg (round 6: forcing it spills to scratch).
__global__ __launch_bounds__(256) void gate_v9_kernel(const float* __restrict__ x,
                                                      const float* __restrict__ wn,
                                                      const float* __restrict__ prep,
                                                      float* __restrict__ out) {
    // smem floats:
    //  [0..8703]   xs: wave w at w*2176, layout [2 buf][16 k][68 tok+pad]
    //  overlay after GEMM: plane region A [64][68] at 0, region B at 4352
    //  [8704..8959] ss_part[4][64]
    __shared__ __align__(16) float smem[8960];
    float* ss_part = smem + 8704;

    const int tid  = threadIdx.x;
    const int lane = tid & 63;
    const int wv   = tid >> 6;            // 0..3 (k-quarter)
    const int tg   = lane >> 3;           // token group 0..7
    const int eg   = lane & 7;            // expert group
    const int e0   = eg * 8;
    const int tbase = blockIdx.x * 64;

    float* xsw = smem + wv * 2176;        // this wave's [2][16][68] tile

    // staging: lane stages its own token row (k-range of this wave)
    const float4* xq4 = (const float4*)(x + (size_t)(tbase + lane) * HID + wv * 256);

    float acc[8][8];
#pragma unroll
    for (int t = 0; t < 8; ++t)
#pragma unroll
        for (int e = 0; e < 8; ++e) acc[t][e] = 0.f;
    float ss = 0.f;

    // ---- prologue: stage chunk 0 (16 k), fuse ss (k-ascending within quarter)
    {
        float4 st[4];
#pragma unroll
        for (int q = 0; q < 4; ++q) st[q] = xq4[q];
#pragma unroll
        for (int q = 0; q < 4; ++q) {
            ss = fmaf(st[q].x, st[q].x, ss);
            ss = fmaf(st[q].y, st[q].y, ss);
            ss = fmaf(st[q].z, st[q].z, ss);
            ss = fmaf(st[q].w, st[q].w, ss);
            xsw[(q * 4 + 0) * 68 + lane] = st[q].x;
            xsw[(q * 4 + 1) * 68 + lane] = st[q].y;
            xsw[(q * 4 + 2) * 68 + lane] = st[q].z;
            xsw[(q * 4 + 3) * 68 + lane] = st[q].w;
        }
    }

#define FMA8x8(XA, XB, WA, WB)                                              \
    do {                                                                    \
        const float xv_[8] = { XA.x, XA.y, XA.z, XA.w, XB.x, XB.y, XB.z, XB.w }; \
        const float wv_[8] = { WA.x, WA.y, WA.z, WA.w, WB.x, WB.y, WB.z, WB.w }; \
        _Pragma("unroll")                                                   \
        for (int t_ = 0; t_ < 8; ++t_)                                      \
            _Pragma("unroll")                                               \
            for (int e_ = 0; e_ < 8; ++e_)                                  \
                acc[t_][e_] = fmaf(xv_[t_], wv_[e_], acc[t_][e_]);          \
    } while (0)

#pragma unroll 1
    for (int c = 0; c < 16; ++c) {
        // issue next chunk's x loads early (consumed after compute)
        float4 st[4];
        if (c < 15) {
#pragma unroll
            for (int q = 0; q < 4; ++q) st[q] = xq4[(c + 1) * 4 + q];
        }

        const float* xb = xsw + (c & 1) * 1088;
        const float* wbase = wn + (size_t)(wv * 256 + c * 16) * NEXP + e0;

        // W prefetch pipeline, depth 2 k-steps
        float4 a0 = *(const float4*)(wbase);
        float4 b0 = *(const float4*)(wbase + 4);
        float4 a1 = *(const float4*)(wbase + 64);
        float4 b1 = *(const float4*)(wbase + 68);

#pragma unroll 4
        for (int k = 0; k < 16; k += 2) {
            float4 na0, nb0, na1, nb1;
            if (k + 2 < 16) {
                na0 = *(const float4*)(wbase + (k + 2) * 64);
                nb0 = *(const float4*)(wbase + (k + 2) * 64 + 4);
                na1 = *(const float4*)(wbase + (k + 3) * 64);
                nb1 = *(const float4*)(wbase + (k + 3) * 64 + 4);
            }
            const float4 xa0 = *(const float4*)&xb[k * 68 + tg * 8];
            const float4 xb0 = *(const float4*)&xb[k * 68 + tg * 8 + 4];
            const float4 xa1 = *(const float4*)&xb[(k + 1) * 68 + tg * 8];
            const float4 xb1 = *(const float4*)&xb[(k + 1) * 68 + tg * 8 + 4];
            FMA8x8(xa0, xb0, a0, b0);
            FMA8x8(xa1, xb1, a1, b1);
            a0 = na0; b0 = nb0; a1 = na1; b1 = nb1;
        }

        // stage chunk c+1 into the other buffer, fuse ss
        if (c < 15) {
            float* xn = xsw + ((c + 1) & 1) * 1088;
#pragma unroll
            for (int q = 0; q < 4; ++q) {
                ss = fmaf(st[q].x, st[q].x, ss);
                ss = fmaf(st[q].y, st[q].y, ss);
                ss = fmaf(st[q].z, st[q].z, ss);
                ss = fmaf(st[q].w, st[q].w, ss);
                xn[(q * 4 + 0) * 68 + lane] = st[q].x;
                xn[(q * 4 + 1) * 68 + lane] = st[q].y;
                xn[(q * 4 + 2) * 68 + lane] = st[q].z;
                xn[(q * 4 + 3) * 68 + lane] = st[q].w;
            }
        }
    }
#undef FMA8x8

    // ---- combine the four k-quarter partials via plane overlay in xs ----
    ss_part[wv * 64 + lane] = ss;         // partial row-norm (lane = own token)
    __syncthreads();                      // all GEMM + staging writes done

    if (wv < 2) {
        // waves 0,1 write their planes to regions A(0)/B(1)
        float* reg = smem + wv * 4352;
#pragma unroll
        for (int j = 0; j < 8; ++j) {
            float* p = &reg[(tg * 8 + j) * 68 + e0];
            *(float4*)(p)     = make_float4(acc[j][0], acc[j][1], acc[j][2], acc[j][3]);
            *(float4*)(p + 4) = make_float4(acc[j][4], acc[j][5], acc[j][6], acc[j][7]);
        }
    }
    __syncthreads();
    if (wv >= 2) {
        // waves 2,3 add their partials: region A = k0+k2, region B = k1+k3
        float* reg = smem + (wv - 2) * 4352;
#pragma unroll
        for (int j = 0; j < 8; ++j) {
            float* p = &reg[(tg * 8 + j) * 68 + e0];
            float4 p0 = *(const float4*)(p);
            float4 p1 = *(const float4*)(p + 4);
            p0.x += acc[j][0]; p0.y += acc[j][1]; p0.z += acc[j][2]; p0.w += acc[j][3];
            p1.x += acc[j][4]; p1.y += acc[j][5]; p1.z += acc[j][6]; p1.w += acc[j][7];
            *(float4*)(p)     = p0;
            *(float4*)(p + 4) = p1;
        }
    }
    __syncthreads();

    // ---- epilogue: wave w -> local tokens w*16 .. w*16+15, 2 per lane-group ----
    float thr[8];
#pragma unroll
    for (int i = 0; i < 8; ++i) thr[i] = prep[64 + e0 + i];

    const size_t out_pre  = (size_t)N_TOK * NEXP;
    const size_t out_mask = 2 * (size_t)N_TOK * NEXP;
    const float* regA = smem;
    const float* regB = smem + 4352;

#pragma unroll
    for (int j = 0; j < 2; ++j) {
        const int tl = wv * 16 + tg * 2 + j;          // local token 0..63
        const int t  = tbase + tl;
        const float sst = (ss_part[tl] + ss_part[64 + tl])
                        + (ss_part[128 + tl] + ss_part[192 + tl]);
        const float inv = 1.0f / fmaxf(sqrtf(sst), EPSF);

        float4 aA0 = *(const float4*)&regA[tl * 68 + e0];
        float4 aA1 = *(const float4*)&regA[tl * 68 + e0 + 4];
        float4 aB0 = *(const float4*)&regB[tl * 68 + e0];
        float4 aB1 = *(const float4*)&regB[tl * 68 + e0 + 4];
        float logit[8] = { (aA0.x + aB0.x) * inv, (aA0.y + aB0.y) * inv,
                           (aA0.z + aB0.z) * inv, (aA0.w + aB0.w) * inv,
                           (aA1.x + aB1.x) * inv, (aA1.y + aB1.y) * inv,
                           (aA1.z + aB1.z) * inv, (aA1.w + aB1.w) * inv };
        float pre[8], gated[8];
        int active[8];
        int myact = 0;
#pragma unroll
        for (int i = 0; i < 8; ++i) {
            pre[i]   = logit[i] - thr[i];
            gated[i] = fmaxf(pre[i], 0.f);
            active[i] = pre[i] > 0.f;
            myact += active[i];
        }
        int rowact = myact;
        rowact += __shfl_xor(rowact, 1, 8);
        rowact += __shfl_xor(rowact, 2, 8);
        rowact += __shfl_xor(rowact, 4, 8);

        float probs[8], mask[8];
        if (rowact > 0) {
            float m = -INFINITY;
#pragma unroll
            for (int i = 0; i < 8; ++i) m = fmaxf(m, active[i] ? gated[i] : -INFINITY);
            m = fmaxf(m, __shfl_xor(m, 1, 8));
            m = fmaxf(m, __shfl_xor(m, 2, 8));
            m = fmaxf(m, __shfl_xor(m, 4, 8));
            float s = 0.f;
#pragma unroll
            for (int i = 0; i < 8; ++i) {
                float ev = active[i] ? expf(gated[i] - m) : 0.f;
                probs[i] = ev; s += ev;
            }
            s += __shfl_xor(s, 1, 8);
            s += __shfl_xor(s, 2, 8);
            s += __shfl_xor(s, 4, 8);
            float rs = 1.0f / s;
#pragma unroll
            for (int i = 0; i < 8; ++i) {
                probs[i] *= rs;
                mask[i] = active[i] ? 1.f : 0.f;
            }
        } else {
            // top-32 fallback: exact 32nd-largest via radix descent on order keys
            unsigned key[8];
#pragma unroll
            for (int i = 0; i < 8; ++i) {
                unsigned u = __float_as_uint(logit[i]);
                key[i] = (u & 0x80000000u) ? ~u : (u | 0x80000000u);
            }
            unsigned cand = 0u;
            for (int bit = 31; bit >= 0; --bit) {
                unsigned test = cand | (1u << bit);
                int c = 0;
#pragma unroll
                for (int i = 0; i < 8; ++i) c += (key[i] >= test);
                c += __shfl_xor(c, 1, 8);
                c += __shfl_xor(c, 2, 8);
                c += __shfl_xor(c, 4, 8);
                if (c >= 32) cand = test;
            }
            int cgt = 0;
#pragma unroll
            for (int i = 0; i < 8; ++i) cgt += (key[i] > cand);
            cgt += __shfl_xor(cgt, 1, 8);
            cgt += __shfl_xor(cgt, 2, 8);
            cgt += __shfl_xor(cgt, 4, 8);
            int need_eq = 32 - cgt;

            int eqc = 0;
#pragma unroll
            for (int i = 0; i < 8; ++i) eqc += (key[i] == cand);
            int scan = eqc, tmp;
            tmp = __shfl_up(scan, 1, 8); if (eg >= 1) scan += tmp;
            tmp = __shfl_up(scan, 2, 8); if (eg >= 2) scan += tmp;
            tmp = __shfl_up(scan, 4, 8); if (eg >= 4) scan += tmp;
            int run = scan - eqc;   // ties with smaller global index
#pragma unroll
            for (int i = 0; i < 8; ++i) {
                int sel = (key[i] > cand) || ((key[i] == cand) && (run < need_eq));
                run += (key[i] == cand);
                mask[i]  = sel ? 1.f : 0.f;
                probs[i] = sel ? 0.03125f : 0.f;   // gated==0 on fallback rows
            }
        }

        const size_t row = (size_t)t * NEXP + e0;
        *(float4*)&out[row]                = make_float4(probs[0], probs[1], probs[2], probs[3]);
        *(float4*)&out[row + 4]            = make_float4(probs[4], probs[5], probs[6], probs[7]);
        *(float4*)&out[out_pre + row]      = make_float4(pre[0], pre[1], pre[2], pre[3]);
        *(float4*)&out[out_pre + row + 4]  = make_float4(pre[4], pre[5], pre[6], pre[7]);
        *(float4*)&out[out_mask + row]     = make_float4(mask[0], mask[1], mask[2], mask[3]);
        *(float4*)&out[out_mask + row + 4] = make_float4(mask[4], mask[5], mask[6], mask[7]);
    }
}

// ---------------- fallback (verbatim round-1 kernel, used only if ws too small)
#define TOKB    128
#define KC      64
#define XPAD    65

__global__ __launch_bounds__(256) void gate_kernel_fb(const float* __restrict__ x,
                                                      const float* __restrict__ sim,
                                                      const float* __restrict__ prep,
                                                      float* __restrict__ out) {
    __shared__ float x_lds[TOKB][XPAD];
    __shared__ float w_lds[KC][NEXP];
    __shared__ float ss_lds[TOKB];
    __shared__ float invcol[NEXP];
    __shared__ float thr_s[NEXP];

    const int tid = threadIdx.x;
    const int base_t = blockIdx.x * TOKB;

    if (tid < NEXP) { invcol[tid] = prep[tid]; thr_s[tid] = prep[64 + tid]; }
    if (tid < TOKB) ss_lds[tid] = 0.f;

    const int g_e = tid & 7;
    const int g_t = tid >> 3;
    const int e0 = g_e * 8;
    const int t0 = g_t * 4;

    const int lt = tid >> 4;
    const int lk = (tid & 15) * 4;

    float acc[4][8];
#pragma unroll
    for (int j = 0; j < 4; ++j)
#pragma unroll
        for (int i = 0; i < 8; ++i) acc[j][i] = 0.f;

    for (int kc = 0; kc < HID; kc += KC) {
        __syncthreads();
#pragma unroll
        for (int it = 0; it < 4; ++it) {
            int flat4 = it * 256 + tid;
            int k = flat4 >> 4;
            int e = (flat4 & 15) * 4;
            float4 v = *(const float4*)&sim[(size_t)(kc + k) * NEXP + e];
            v.x *= invcol[e]; v.y *= invcol[e + 1]; v.z *= invcol[e + 2]; v.w *= invcol[e + 3];
            *(float4*)&w_lds[k][e] = v;
        }
#pragma unroll
        for (int it = 0; it < 8; ++it) {
            int t = it * 16 + lt;
            float4 v = *(const float4*)&x[(size_t)(base_t + t) * HID + kc + lk];
            x_lds[t][lk + 0] = v.x; x_lds[t][lk + 1] = v.y;
            x_lds[t][lk + 2] = v.z; x_lds[t][lk + 3] = v.w;
            float s4 = v.x * v.x + v.y * v.y + v.z * v.z + v.w * v.w;
            s4 += __shfl_xor(s4, 1, 16);
            s4 += __shfl_xor(s4, 2, 16);
            s4 += __shfl_xor(s4, 4, 16);
            s4 += __shfl_xor(s4, 8, 16);
            if ((tid & 15) == 0) ss_lds[t] += s4;
        }
        __syncthreads();
#pragma unroll 8
        for (int k = 0; k < KC; ++k) {
            float x0 = x_lds[t0 + 0][k];
            float x1 = x_lds[t0 + 1][k];
            float x2 = x_lds[t0 + 2][k];
            float x3 = x_lds[t0 + 3][k];
            float4 w0 = *(const float4*)&w_lds[k][e0];
            float4 w1 = *(const float4*)&w_lds[k][e0 + 4];
            float wv[8] = { w0.x, w0.y, w0.z, w0.w, w1.x, w1.y, w1.z, w1.w };
#pragma unroll
            for (int i = 0; i < 8; ++i) {
                acc[0][i] += x0 * wv[i];
                acc[1][i] += x1 * wv[i];
                acc[2][i] += x2 * wv[i];
                acc[3][i] += x3 * wv[i];
            }
        }
    }

    const size_t out_pre  = (size_t)N_TOK * NEXP;
    const size_t out_mask = 2 * (size_t)N_TOK * NEXP;

#pragma unroll
    for (int j = 0; j < 4; ++j) {
        int t = t0 + j;
        float inv = 1.0f / fmaxf(sqrtf(ss_lds[t]), EPSF);
        float logit[8], pre[8], gated[8];
        int active[8];
        int myact = 0;
#pragma unroll
        for (int i = 0; i < 8; ++i) {
            logit[i] = acc[j][i] * inv;
            pre[i]   = logit[i] - thr_s[e0 + i];
            gated[i] = fmaxf(pre[i], 0.f);
            active[i] = pre[i] > 0.f;
            myact += active[i];
        }
        int rowact = myact;
        rowact += __shfl_xor(rowact, 1, 8);
        rowact += __shfl_xor(rowact, 2, 8);
        rowact += __shfl_xor(rowact, 4, 8);

        float probs[8], mask[8];
        if (rowact > 0) {
            float m = -INFINITY;
#pragma unroll
            for (int i = 0; i < 8; ++i) m = fmaxf(m, active[i] ? gated[i] : -INFINITY);
            m = fmaxf(m, __shfl_xor(m, 1, 8));
            m = fmaxf(m, __shfl_xor(m, 2, 8));
            m = fmaxf(m, __shfl_xor(m, 4, 8));
            float s = 0.f;
#pragma unroll
            for (int i = 0; i < 8; ++i) {
                float ev = active[i] ? expf(gated[i] - m) : 0.f;
                probs[i] = ev; s += ev;
            }
            s += __shfl_xor(s, 1, 8);
            s += __shfl_xor(s, 2, 8);
            s += __shfl_xor(s, 4, 8);
            float rs = 1.0f / s;
#pragma unroll
            for (int i = 0; i < 8; ++i) {
                probs[i] *= rs;
                mask[i] = active[i] ? 1.f : 0.f;
            }
        } else {
            unsigned key[8];
#pragma unroll
            for (int i = 0; i < 8; ++i) {
                unsigned u = __float_as_uint(logit[i]);
                key[i] = (u & 0x80000000u) ? ~u : (u | 0x80000000u);
            }
            unsigned cand = 0u;
            for (int bit = 31; bit >= 0; --bit) {
                unsigned test = cand | (1u << bit);
                int c = 0;
#pragma unroll
                for (int i = 0; i < 8; ++i) c += (key[i] >= test);
                c += __shfl_xor(c, 1, 8);
                c += __shfl_xor(c, 2, 8);
                c += __shfl_xor(c, 4, 8);
                if (c >= 32) cand = test;
            }
            int cgt = 0;
#pragma unroll
            for (int i = 0; i < 8; ++i) cgt += (key[i] > cand);
            cgt += __shfl_xor(cgt, 1, 8);
            cgt += __shfl_xor(cgt, 2, 8);
            cgt += __shfl_xor(cgt, 4, 8);
            int need_eq = 32 - cgt;

            int eqc = 0;
#pragma unroll
            for (int i = 0; i < 8; ++i) eqc += (key[i] == cand);
            int scan = eqc, tmp;
            tmp = __shfl_up(scan, 1, 8); if (g_e >= 1) scan += tmp;
            tmp = __shfl_up(scan, 2, 8); if (g_e >= 2) scan += tmp;
            tmp = __shfl_up(scan, 4, 8); if (g_e >= 4) scan += tmp;
            int run = scan - eqc;
#pragma unroll
            for (int i = 0; i < 8; ++i) {
                int sel = (key[i] > cand) || ((key[i] == cand) && (run < need_eq));
                run += (key[i] == cand);
                mask[i]  = sel ? 1.f : 0.f;
                probs[i] = sel ? 0.03125f : 0.f;
            }
        }

        size_t row = (size_t)(base_t + t) * NEXP + e0;
        *(float4*)&out[row]                = make_float4(probs[0], probs[1], probs[2], probs[3]);
        *(float4*)&out[row + 4]            = make_float4(probs[4], probs[5], probs[6], probs[7]);
        *(float4*)&out[out_pre + row]      = make_float4(pre[0], pre[1], pre[2], pre[3]);
        *(float4*)&out[out_pre + row + 4]  = make_float4(pre[4], pre[5], pre[6], pre[7]);
        *(float4*)&out[out_mask + row]     = make_float4(mask[0], mask[1], mask[2], mask[3]);
        *(float4*)&out[out_mask + row + 4] = make_float4(mask[4], mask[5], mask[6], mask[7]);
    }
}

extern "C" void kernel_launch(void* const* d_in, const int* in_sizes, int n_in,
                              void* d_out, int out_size, void* d_ws, size_t ws_size,
                              hipStream_t stream) {
    (void)in_sizes; (void)n_in; (void)out_size;
    const float* x     = (const float*)d_in[0];
    const float* sim   = (const float*)d_in[1];
    const float* gates = (const float*)d_in[2];
    float* out = (float*)d_out;
    float* ws  = (float*)d_ws;

    hipLaunchKernelGGL(prep_kernel, dim3(1), dim3(256), 0, stream, sim, gates, ws);

    const size_t need = 512 + (size_t)HID * NEXP * sizeof(float);   // prep + wn
    if (ws_size >= need) {
        float* wn = ws + 128;
        hipLaunchKernelGGL(prep2n_kernel, dim3(HID * NEXP / 256), dim3(256), 0, stream,
                           sim, ws, wn);
        hipLaunchKernelGGL(gate_v9_kernel, dim3(N_TOK / 64), dim3(256), 0, stream,
                           x, wn, ws, out);
    } else {
        hipLaunchKernelGGL(gate_kernel_fb, dim3(N_TOK / TOKB), dim3(256), 0, stream,
                           x, sim, ws, out);
    }
}

// Round 10
// 161.487 us; speedup vs baseline: 13.0875x; 1.0819x over previous
//
#include <hip/hip_runtime.h>
#include <math.h>

#define N_TOK   65536
#define HID     1024
#define NEXP    64
#define EPSF    1e-12f

// ---------------- prep: ws[0..63] = 1/||sim col||, ws[64..127] = sigmoid(gates)
__global__ __launch_bounds__(256) void prep_kernel(const float* __restrict__ sim,
                                                   const float* __restrict__ gates,
                                                   float* __restrict__ ws) {
    __shared__ float partial[4][64];
    int e = threadIdx.x & 63;
    int q = threadIdx.x >> 6;   // 0..3
    float s = 0.f;
    for (int h = q * 256; h < q * 256 + 256; ++h) {
        float v = sim[h * NEXP + e];
        s += v * v;
    }
    partial[q][e] = s;
    __syncthreads();
    if (threadIdx.x < 64) {
        float ss = partial[0][e] + partial[1][e] + partial[2][e] + partial[3][e];
        ws[e] = 1.0f / fmaxf(sqrtf(ss), EPSF);
        ws[64 + e] = 1.0f / (1.0f + expf(-gates[e]));
    }
}

// ---------------- prep2: natural-layout normalized W: wn[k*64+e] = sim[k*64+e]*invcol[e]
__global__ __launch_bounds__(256) void prep2n_kernel(const float* __restrict__ sim,
                                                     const float* __restrict__ ws_ro,
                                                     float* __restrict__ wn) {
    int idx = blockIdx.x * 256 + threadIdx.x;   // 0..65535
    wn[idx] = sim[idx] * ws_ro[idx & 63];
}

// ---------------- main kernel v10: R9 structure, but W staged in per-wave LDS
// (kills the 8x-duplicated W VMEM stream that saturated L1 in R9).
// 256 threads = 4 waves, K-split by 4; chunk = 8 k double-buffered.
// Per-wave LDS region (2112 floats): xs [2][8][68] (544 each) at 0,
// W [2][8][64] (512 each) at 1088. ss_part[4][64] after all regions.
// Plane overlay after GEMM: region A [64][65] at 0, region B at 4224.
// NOTE: no min-waves launch-bounds arg (round 6: forcing it spills to scratch).
__global__ __launch_bounds__(256) void gate_v10_kernel(const float* __restrict__ x,
                                                       const float* __restrict__ wn,
                                                       const float* __restrict__ prep,
                                                       float* __restrict__ out) {
    __shared__ __align__(16) float smem[8704];   // 8448 tile + 256 ss_part
    float* ss_part = smem + 8448;

    const int tid  = threadIdx.x;
    const int lane = tid & 63;
    const int wv   = tid >> 6;            // 0..3 (k-quarter)
    const int tg   = lane >> 3;           // token group 0..7
    const int eg   = lane & 7;            // expert group
    const int e0   = eg * 8;
    const int tbase = blockIdx.x * 64;
    const int kbase = wv * 256;

    float* xsw = smem + wv * 2112;        // this wave's private region

    // staging sources: lane's own token row (k-quarter), and W k-quarter slab
    const float4* xq4 = (const float4*)(x + (size_t)(tbase + lane) * HID + kbase);

    float acc[8][8];
#pragma unroll
    for (int t = 0; t < 8; ++t)
#pragma unroll
        for (int e = 0; e < 8; ++e) acc[t][e] = 0.f;
    float ss = 0.f;

    // ---- prologue: stage chunk 0 (8 k of x + 2KB of W), fuse ss ----
    {
        float4 f0 = xq4[0], f1 = xq4[1];
        const float4* wq4 = (const float4*)(wn + (size_t)kbase * NEXP) + lane * 2;
        float4 w0 = wq4[0], w1 = wq4[1];
        const float a[8] = { f0.x, f0.y, f0.z, f0.w, f1.x, f1.y, f1.z, f1.w };
#pragma unroll
        for (int i = 0; i < 8; ++i) {
            ss = fmaf(a[i], a[i], ss);
            xsw[i * 68 + lane] = a[i];
        }
        *(float4*)&xsw[1088 + lane * 8]     = w0;
        *(float4*)&xsw[1088 + lane * 8 + 4] = w1;
    }

#define FMA8x8(XA, XB, WA, WB)                                              \
    do {                                                                    \
        const float xv_[8] = { XA.x, XA.y, XA.z, XA.w, XB.x, XB.y, XB.z, XB.w }; \
        const float wv_[8] = { WA.x, WA.y, WA.z, WA.w, WB.x, WB.y, WB.z, WB.w }; \
        _Pragma("unroll")                                                   \
        for (int t_ = 0; t_ < 8; ++t_)                                      \
            _Pragma("unroll")                                               \
            for (int e_ = 0; e_ < 8; ++e_)                                  \
                acc[t_][e_] = fmaf(xv_[t_], wv_[e_], acc[t_][e_]);          \
    } while (0)

#pragma unroll 1
    for (int c = 0; c < 32; ++c) {
        // issue next chunk's global loads early (consumed after compute)
        float4 sx0, sx1, sw0, sw1;
        if (c < 31) {
            sx0 = xq4[(c + 1) * 2];
            sx1 = xq4[(c + 1) * 2 + 1];
            const float4* wq4 = (const float4*)(wn + (size_t)(kbase + (c + 1) * 8) * NEXP)
                              + lane * 2;
            sw0 = wq4[0];
            sw1 = wq4[1];
        }

        const float* xb = xsw + (c & 1) * 544;
        const float* wb = xsw + 1088 + (c & 1) * 512;

#pragma unroll
        for (int k = 0; k < 8; ++k) {
            const float4 xa = *(const float4*)&xb[k * 68 + tg * 8];
            const float4 xc = *(const float4*)&xb[k * 68 + tg * 8 + 4];
            const float4 wa = *(const float4*)&wb[k * 64 + e0];
            const float4 wc = *(const float4*)&wb[k * 64 + e0 + 4];
            FMA8x8(xa, xc, wa, wc);
        }

        // stage chunk c+1 into the other buffers, fuse ss (DS in-order per wave)
        if (c < 31) {
            float* xn = xsw + ((c + 1) & 1) * 544;
            float* wl = xsw + 1088 + ((c + 1) & 1) * 512;
            const float a[8] = { sx0.x, sx0.y, sx0.z, sx0.w, sx1.x, sx1.y, sx1.z, sx1.w };
#pragma unroll
            for (int i = 0; i < 8; ++i) {
                ss = fmaf(a[i], a[i], ss);
                xn[i * 68 + lane] = a[i];
            }
            *(float4*)&wl[lane * 8]     = sw0;
            *(float4*)&wl[lane * 8 + 4] = sw1;
        }
    }
#undef FMA8x8

    // ---- combine the four k-quarter partials via plane overlay ----
    ss_part[wv * 64 + lane] = ss;         // partial row-norm (lane = own token)
    __syncthreads();                      // all GEMM + staging done

    if (wv < 2) {
        // waves 0,1 write planes to regions A(0) / B(4224), stride 65
        float* reg = smem + wv * 4224;
#pragma unroll
        for (int j = 0; j < 8; ++j) {
            float* p = &reg[(tg * 8 + j) * 65 + e0];
            *(float4*)(p)     = make_float4(acc[j][0], acc[j][1], acc[j][2], acc[j][3]);
            *(float4*)(p + 4) = make_float4(acc[j][4], acc[j][5], acc[j][6], acc[j][7]);
        }
    }
    __syncthreads();
    if (wv >= 2) {
        // waves 2,3 add their partials: region A = k0+k2, region B = k1+k3
        float* reg = smem + (wv - 2) * 4224;
#pragma unroll
        for (int j = 0; j < 8; ++j) {
            float* p = &reg[(tg * 8 + j) * 65 + e0];
            float4 p0 = *(const float4*)(p);
            float4 p1 = *(const float4*)(p + 4);
            p0.x += acc[j][0]; p0.y += acc[j][1]; p0.z += acc[j][2]; p0.w += acc[j][3];
            p1.x += acc[j][4]; p1.y += acc[j][5]; p1.z += acc[j][6]; p1.w += acc[j][7];
            *(float4*)(p)     = p0;
            *(float4*)(p + 4) = p1;
        }
    }
    __syncthreads();

    // ---- epilogue: wave w -> local tokens w*16 .. w*16+15 ----
    float thr[8];
#pragma unroll
    for (int i = 0; i < 8; ++i) thr[i] = prep[64 + e0 + i];

    const size_t out_pre  = (size_t)N_TOK * NEXP;
    const size_t out_mask = 2 * (size_t)N_TOK * NEXP;
    const float* regA = smem;
    const float* regB = smem + 4224;

#pragma unroll
    for (int j = 0; j < 2; ++j) {
        const int tl = wv * 16 + tg * 2 + j;          // local token 0..63
        const int t  = tbase + tl;
        const float sst = (ss_part[tl] + ss_part[64 + tl])
                        + (ss_part[128 + tl] + ss_part[192 + tl]);
        const float inv = 1.0f / fmaxf(sqrtf(sst), EPSF);

        float4 aA0 = *(const float4*)&regA[tl * 65 + e0];
        float4 aA1 = *(const float4*)&regA[tl * 65 + e0 + 4];
        float4 aB0 = *(const float4*)&regB[tl * 65 + e0];
        float4 aB1 = *(const float4*)&regB[tl * 65 + e0 + 4];
        float logit[8] = { (aA0.x + aB0.x) * inv, (aA0.y + aB0.y) * inv,
                           (aA0.z + aB0.z) * inv, (aA0.w + aB0.w) * inv,
                           (aA1.x + aB1.x) * inv, (aA1.y + aB1.y) * inv,
                           (aA1.z + aB1.z) * inv, (aA1.w + aB1.w) * inv };
        float pre[8], gated[8];
        int active[8];
        int myact = 0;
#pragma unroll
        for (int i = 0; i < 8; ++i) {
            pre[i]   = logit[i] - thr[i];
            gated[i] = fmaxf(pre[i], 0.f);
            active[i] = pre[i] > 0.f;
            myact += active[i];
        }
        int rowact = myact;
        rowact += __shfl_xor(rowact, 1, 8);
        rowact += __shfl_xor(rowact, 2, 8);
        rowact += __shfl_xor(rowact, 4, 8);

        float probs[8], mask[8];
        if (rowact > 0) {
            float m = -INFINITY;
#pragma unroll
            for (int i = 0; i < 8; ++i) m = fmaxf(m, active[i] ? gated[i] : -INFINITY);
            m = fmaxf(m, __shfl_xor(m, 1, 8));
            m = fmaxf(m, __shfl_xor(m, 2, 8));
            m = fmaxf(m, __shfl_xor(m, 4, 8));
            float s = 0.f;
#pragma unroll
            for (int i = 0; i < 8; ++i) {
                float ev = active[i] ? expf(gated[i] - m) : 0.f;
                probs[i] = ev; s += ev;
            }
            s += __shfl_xor(s, 1, 8);
            s += __shfl_xor(s, 2, 8);
            s += __shfl_xor(s, 4, 8);
            float rs = 1.0f / s;
#pragma unroll
            for (int i = 0; i < 8; ++i) {
                probs[i] *= rs;
                mask[i] = active[i] ? 1.f : 0.f;
            }
        } else {
            // top-32 fallback: exact 32nd-largest via radix descent on order keys
            unsigned key[8];
#pragma unroll
            for (int i = 0; i < 8; ++i) {
                unsigned u = __float_as_uint(logit[i]);
                key[i] = (u & 0x80000000u) ? ~u : (u | 0x80000000u);
            }
            unsigned cand = 0u;
            for (int bit = 31; bit >= 0; --bit) {
                unsigned test = cand | (1u << bit);
                int c = 0;
#pragma unroll
                for (int i = 0; i < 8; ++i) c += (key[i] >= test);
                c += __shfl_xor(c, 1, 8);
                c += __shfl_xor(c, 2, 8);
                c += __shfl_xor(c, 4, 8);
                if (c >= 32) cand = test;
            }
            int cgt = 0;
#pragma unroll
            for (int i = 0; i < 8; ++i) cgt += (key[i] > cand);
            cgt += __shfl_xor(cgt, 1, 8);
            cgt += __shfl_xor(cgt, 2, 8);
            cgt += __shfl_xor(cgt, 4, 8);
            int need_eq = 32 - cgt;

            int eqc = 0;
#pragma unroll
            for (int i = 0; i < 8; ++i) eqc += (key[i] == cand);
            int scan = eqc, tmp;
            tmp = __shfl_up(scan, 1, 8); if (eg >= 1) scan += tmp;
            tmp = __shfl_up(scan, 2, 8); if (eg >= 2) scan += tmp;
            tmp = __shfl_up(scan, 4, 8); if (eg >= 4) scan += tmp;
            int run = scan - eqc;   // ties with smaller global index
#pragma unroll
            for (int i = 0; i < 8; ++i) {
                int sel = (key[i] > cand) || ((key[i] == cand) && (run < need_eq));
                run += (key[i] == cand);
                mask[i]  = sel ? 1.f : 0.f;
                probs[i] = sel ? 0.03125f : 0.f;   // gated==0 on fallback rows
            }
        }

        const size_t row = (size_t)t * NEXP + e0;
        *(float4*)&out[row]                = make_float4(probs[0], probs[1], probs[2], probs[3]);
        *(float4*)&out[row + 4]            = make_float4(probs[4], probs[5], probs[6], probs[7]);
        *(float4*)&out[out_pre + row]      = make_float4(pre[0], pre[1], pre[2], pre[3]);
        *(float4*)&out[out_pre + row + 4]  = make_float4(pre[4], pre[5], pre[6], pre[7]);
        *(float4*)&out[out_mask + row]     = make_float4(mask[0], mask[1], mask[2], mask[3]);
        *(float4*)&out[out_mask + row + 4] = make_float4(mask[4], mask[5], mask[6], mask[7]);
    }
}

// ---------------- fallback (verbatim round-1 kernel, used only if ws too small)
#define TOKB    128
#define KC      64
#define XPAD    65

__global__ __launch_bounds__(256) void gate_kernel_fb(const float* __restrict__ x,
                                                      const float* __restrict__ sim,
                                                      const float* __restrict__ prep,
                                                      float* __restrict__ out) {
    __shared__ float x_lds[TOKB][XPAD];
    __shared__ float w_lds[KC][NEXP];
    __shared__ float ss_lds[TOKB];
    __shared__ float invcol[NEXP];
    __shared__ float thr_s[NEXP];

    const int tid = threadIdx.x;
    const int base_t = blockIdx.x * TOKB;

    if (tid < NEXP) { invcol[tid] = prep[tid]; thr_s[tid] = prep[64 + tid]; }
    if (tid < TOKB) ss_lds[tid] = 0.f;

    const int g_e = tid & 7;
    const int g_t = tid >> 3;
    const int e0 = g_e * 8;
    const int t0 = g_t * 4;

    const int lt = tid >> 4;
    const int lk = (tid & 15) * 4;

    float acc[4][8];
#pragma unroll
    for (int j = 0; j < 4; ++j)
#pragma unroll
        for (int i = 0; i < 8; ++i) acc[j][i] = 0.f;

    for (int kc = 0; kc < HID; kc += KC) {
        __syncthreads();
#pragma unroll
        for (int it = 0; it < 4; ++it) {
            int flat4 = it * 256 + tid;
            int k = flat4 >> 4;
            int e = (flat4 & 15) * 4;
            float4 v = *(const float4*)&sim[(size_t)(kc + k) * NEXP + e];
            v.x *= invcol[e]; v.y *= invcol[e + 1]; v.z *= invcol[e + 2]; v.w *= invcol[e + 3];
            *(float4*)&w_lds[k][e] = v;
        }
#pragma unroll
        for (int it = 0; it < 8; ++it) {
            int t = it * 16 + lt;
            float4 v = *(const float4*)&x[(size_t)(base_t + t) * HID + kc + lk];
            x_lds[t][lk + 0] = v.x; x_lds[t][lk + 1] = v.y;
            x_lds[t][lk + 2] = v.z; x_lds[t][lk + 3] = v.w;
            float s4 = v.x * v.x + v.y * v.y + v.z * v.z + v.w * v.w;
            s4 += __shfl_xor(s4, 1, 16);
            s4 += __shfl_xor(s4, 2, 16);
            s4 += __shfl_xor(s4, 4, 16);
            s4 += __shfl_xor(s4, 8, 16);
            if ((tid & 15) == 0) ss_lds[t] += s4;
        }
        __syncthreads();
#pragma unroll 8
        for (int k = 0; k < KC; ++k) {
            float x0 = x_lds[t0 + 0][k];
            float x1 = x_lds[t0 + 1][k];
            float x2 = x_lds[t0 + 2][k];
            float x3 = x_lds[t0 + 3][k];
            float4 w0 = *(const float4*)&w_lds[k][e0];
            float4 w1 = *(const float4*)&w_lds[k][e0 + 4];
            float wv[8] = { w0.x, w0.y, w0.z, w0.w, w1.x, w1.y, w1.z, w1.w };
#pragma unroll
            for (int i = 0; i < 8; ++i) {
                acc[0][i] += x0 * wv[i];
                acc[1][i] += x1 * wv[i];
                acc[2][i] += x2 * wv[i];
                acc[3][i] += x3 * wv[i];
            }
        }
    }

    const size_t out_pre  = (size_t)N_TOK * NEXP;
    const size_t out_mask = 2 * (size_t)N_TOK * NEXP;

#pragma unroll
    for (int j = 0; j < 4; ++j) {
        int t = t0 + j;
        float inv = 1.0f / fmaxf(sqrtf(ss_lds[t]), EPSF);
        float logit[8], pre[8], gated[8];
        int active[8];
        int myact = 0;
#pragma unroll
        for (int i = 0; i < 8; ++i) {
            logit[i] = acc[j][i] * inv;
            pre[i]   = logit[i] - thr_s[e0 + i];
            gated[i] = fmaxf(pre[i], 0.f);
            active[i] = pre[i] > 0.f;
            myact += active[i];
        }
        int rowact = myact;
        rowact += __shfl_xor(rowact, 1, 8);
        rowact += __shfl_xor(rowact, 2, 8);
        rowact += __shfl_xor(rowact, 4, 8);

        float probs[8], mask[8];
        if (rowact > 0) {
            float m = -INFINITY;
#pragma unroll
            for (int i = 0; i < 8; ++i) m = fmaxf(m, active[i] ? gated[i] : -INFINITY);
            m = fmaxf(m, __shfl_xor(m, 1, 8));
            m = fmaxf(m, __shfl_xor(m, 2, 8));
            m = fmaxf(m, __shfl_xor(m, 4, 8));
            float s = 0.f;
#pragma unroll
            for (int i = 0; i < 8; ++i) {
                float ev = active[i] ? expf(gated[i] - m) : 0.f;
                probs[i] = ev; s += ev;
            }
            s += __shfl_xor(s, 1, 8);
            s += __shfl_xor(s, 2, 8);
            s += __shfl_xor(s, 4, 8);
            float rs = 1.0f / s;
#pragma unroll
            for (int i = 0; i < 8; ++i) {
                probs[i] *= rs;
                mask[i] = active[i] ? 1.f : 0.f;
            }
        } else {
            unsigned key[8];
#pragma unroll
            for (int i = 0; i < 8; ++i) {
                unsigned u = __float_as_uint(logit[i]);
                key[i] = (u & 0x80000000u) ? ~u : (u | 0x80000000u);
            }
            unsigned cand = 0u;
            for (int bit = 31; bit >= 0; --bit) {
                unsigned test = cand | (1u << bit);
                int c = 0;
#pragma unroll
                for (int i = 0; i < 8; ++i) c += (key[i] >= test);
                c += __shfl_xor(c, 1, 8);
                c += __shfl_xor(c, 2, 8);
                c += __shfl_xor(c, 4, 8);
                if (c >= 32) cand = test;
            }
            int cgt = 0;
#pragma unroll
            for (int i = 0; i < 8; ++i) cgt += (key[i] > cand);
            cgt += __shfl_xor(cgt, 1, 8);
            cgt += __shfl_xor(cgt, 2, 8);
            cgt += __shfl_xor(cgt, 4, 8);
            int need_eq = 32 - cgt;

            int eqc = 0;
#pragma unroll
            for (int i = 0; i < 8; ++i) eqc += (key[i] == cand);
            int scan = eqc, tmp;
            tmp = __shfl_up(scan, 1, 8); if (g_e >= 1) scan += tmp;
            tmp = __shfl_up(scan, 2, 8); if (g_e >= 2) scan += tmp;
            tmp = __shfl_up(scan, 4, 8); if (g_e >= 4) scan += tmp;
            int run = scan - eqc;
#pragma unroll
            for (int i = 0; i < 8; ++i) {
                int sel = (key[i] > cand) || ((key[i] == cand) && (run < need_eq));
                run += (key[i] == cand);
                mask[i]  = sel ? 1.f : 0.f;
                probs[i] = sel ? 0.03125f : 0.f;
            }
        }

        size_t row = (size_t)(base_t + t) * NEXP + e0;
        *(float4*)&out[row]                = make_float4(probs[0], probs[1], probs[2], probs[3]);
        *(float4*)&out[row + 4]            = make_float4(probs[4], probs[5], probs[6], probs[7]);
        *(float4*)&out[out_pre + row]      = make_float4(pre[0], pre[1], pre[2], pre[3]);
        *(float4*)&out[out_pre + row + 4]  = make_float4(pre[4], pre[5], pre[6], pre[7]);
        *(float4*)&out[out_mask + row]     = make_float4(mask[0], mask[1], mask[2], mask[3]);
        *(float4*)&out[out_mask + row + 4] = make_float4(mask[4], mask[5], mask[6], mask[7]);
    }
}

extern "C" void kernel_launch(void* const* d_in, const int* in_sizes, int n_in,
                              void* d_out, int out_size, void* d_ws, size_t ws_size,
                              hipStream_t stream) {
    (void)in_sizes; (void)n_in; (void)out_size;
    const float* x     = (const float*)d_in[0];
    const float* sim   = (const float*)d_in[1];
    const float* gates = (const float*)d_in[2];
    float* out = (float*)d_out;
    float* ws  = (float*)d_ws;

    hipLaunchKernelGGL(prep_kernel, dim3(1), dim3(256), 0, stream, sim, gates, ws);

    const size_t need = 512 + (size_t)HID * NEXP * sizeof(float);   // prep + wn
    if (ws_size >= need) {
        float* wn = ws + 128;
        hipLaunchKernelGGL(prep2n_kernel, dim3(HID * NEXP / 256), dim3(256), 0, stream,
                           sim, ws, wn);
        hipLaunchKernelGGL(gate_v10_kernel, dim3(N_TOK / 64), dim3(256), 0, stream,
                           x, wn, ws, out);
    } else {
        hipLaunchKernelGGL(gate_kernel_fb, dim3(N_TOK / TOKB), dim3(256), 0, stream,
                           x, sim, ws, out);
    }
}